// Round 3
// baseline (506.200 us; speedup 1.0000x reference)
//
#include <hip/hip_runtime.h>

typedef unsigned int uint;
typedef unsigned short ushort_t;
typedef short bf16x8 __attribute__((ext_vector_type(8)));
typedef float f32x4 __attribute__((ext_vector_type(4)));

// ---------- bf16 helpers ----------
__device__ __forceinline__ ushort_t f2bf(float f) {
  uint u = __builtin_bit_cast(uint, f);
  u += 0x7fffu + ((u >> 16) & 1u);
  return (ushort_t)(u >> 16);
}
__device__ __forceinline__ float bf2f(ushort_t s) {
  return __builtin_bit_cast(float, (uint)s << 16);
}
__device__ __forceinline__ bf16x8 ld_frag(const ushort_t* p) {
  return __builtin_bit_cast(bf16x8, *(const uint4*)p);
}
// force a wave-uniform load into an SGPR (keeps the 6x6 fuse weights off VGPRs)
__device__ __forceinline__ float uload(const float* p) {
  return __builtin_bit_cast(float,
      __builtin_amdgcn_readfirstlane(__builtin_bit_cast(int, *p)));
}

// ---------- Kernel 1: depthwise conv 3x3 s2 p1 + LayerNorm -> bf16 ----------
__global__ __launch_bounds__(384) void k_convln(
    const float* __restrict__ x, const float* __restrict__ wc,
    const float* __restrict__ g, const float* __restrict__ bb,
    ushort_t* __restrict__ qout)
{
  const int b  = blockIdx.x / 784;
  const int t  = blockIdx.x % 784;
  const int oy = t / 28, ox = t % 28;
  const int c  = threadIdx.x;
  const float* xb = x + (size_t)b * 3136 * 384 + c;
  float acc = 0.f;
  #pragma unroll
  for (int ky = 0; ky < 3; ky++) {
    const int iy = 2 * oy - 1 + ky;
    if (iy < 0 || iy >= 56) continue;
    #pragma unroll
    for (int kx = 0; kx < 3; kx++) {
      const int ix = 2 * ox - 1 + kx;
      if (ix < 0 || ix >= 56) continue;
      acc += wc[c * 9 + ky * 3 + kx] * xb[(size_t)(iy * 56 + ix) * 384];
    }
  }
  float s = acc, s2 = acc * acc;
  #pragma unroll
  for (int off = 32; off >= 1; off >>= 1) {
    s  += __shfl_xor(s,  off);
    s2 += __shfl_xor(s2, off);
  }
  __shared__ float ps[6], ps2[6];
  if ((c & 63) == 0) { ps[c >> 6] = s; ps2[c >> 6] = s2; }
  __syncthreads();
  float S = 0.f, S2 = 0.f;
  #pragma unroll
  for (int i = 0; i < 6; i++) { S += ps[i]; S2 += ps2[i]; }
  const float mu  = S * (1.f / 384.f);
  const float var = S2 * (1.f / 384.f) - mu * mu;
  const float inv = rsqrtf(var + 1e-5f);
  qout[((size_t)b * 784 + t) * 384 + c] = f2bf((acc - mu) * inv * g[c] + bb[c]);
}

// ---------- Kernel 2: 2x2 average pool -> bf16 ----------
__global__ __launch_bounds__(256) void k_pool(
    const float* __restrict__ x, ushort_t* __restrict__ kvout)
{
  const int idx = blockIdx.x * 256 + threadIdx.x;
  const int c = idx % 384;
  const int t = (idx / 384) % 784;
  const int b = idx / (384 * 784);
  const int ty = t / 28, tx = t % 28;
  const float* xb = x + (size_t)b * 3136 * 384 + c;
  const int r0 = (2 * ty) * 56 + 2 * tx;
  const float v = xb[(size_t)r0 * 384] + xb[(size_t)(r0 + 1) * 384]
                + xb[(size_t)(r0 + 56) * 384] + xb[(size_t)(r0 + 57) * 384];
  kvout[idx] = f2bf(v * 0.25f);
}

// ---------- Kernel 3: weights f32 -> bf16 ----------
__global__ __launch_bounds__(256) void k_wcvt(
    const float* __restrict__ a, const float* __restrict__ b,
    const float* __restrict__ c, const float* __restrict__ d,
    ushort_t* __restrict__ oa, ushort_t* __restrict__ ob,
    ushort_t* __restrict__ oc, ushort_t* __restrict__ od)
{
  const int i = blockIdx.x * 256 + threadIdx.x;
  if (i < 147456) {
    oa[i] = f2bf(a[i]); ob[i] = f2bf(b[i]);
    oc[i] = f2bf(c[i]); od[i] = f2bf(d[i]);
  }
}

// ---------- Kernel 4: dense MFMA GEMM, M=6272 N=384 K=384 ----------
// Y[m,n] = sum_k X[m,k]*W[n,k]. 128x128 tile, 4 waves (2x2), 4x4 16x16 tiles.
// MODE 0: bf16 row-major out; MODE 1: bf16 transposed (b,384,784) out (for V);
// MODE 2: f32 +bias out.
template<int MODE>
__global__ __launch_bounds__(256) void k_gemm(
    const ushort_t* __restrict__ X, const ushort_t* __restrict__ W,
    const float* __restrict__ bias, void* __restrict__ Y)
{
  __shared__ ushort_t As[128][40];  // pad 32->40: row stride 20 words (2-way, free)
  __shared__ ushort_t Bs[128][40];
  const int tid = threadIdx.x, w = tid >> 6, lane = tid & 63;
  const int quad = lane >> 4, r = lane & 15;
  const int m0 = blockIdx.y * 128, n0 = blockIdx.x * 128;
  const int wm = w >> 1, wn = w & 1;
  const int lr = tid >> 2, lc = (tid & 3) << 3;
  const ushort_t* xp = X + (size_t)(m0 + lr) * 384 + lc;
  const ushort_t* wp = W + (size_t)(n0 + lr) * 384 + lc;
  f32x4 acc[4][4] = {};
  for (int k0 = 0; k0 < 384; k0 += 32) {
    __syncthreads();
    *(uint4*)&As[lr][lc]      = *(const uint4*)(xp + k0);
    *(uint4*)&As[lr + 64][lc] = *(const uint4*)(xp + (size_t)64 * 384 + k0);
    *(uint4*)&Bs[lr][lc]      = *(const uint4*)(wp + k0);
    *(uint4*)&Bs[lr + 64][lc] = *(const uint4*)(wp + (size_t)64 * 384 + k0);
    __syncthreads();
    bf16x8 af[4], bf_[4];
    #pragma unroll
    for (int mt = 0; mt < 4; mt++) af[mt]  = *(const bf16x8*)&As[wm * 64 + mt * 16 + r][quad * 8];
    #pragma unroll
    for (int nt = 0; nt < 4; nt++) bf_[nt] = *(const bf16x8*)&Bs[wn * 64 + nt * 16 + r][quad * 8];
    #pragma unroll
    for (int mt = 0; mt < 4; mt++)
      #pragma unroll
      for (int nt = 0; nt < 4; nt++)
        acc[mt][nt] = __builtin_amdgcn_mfma_f32_16x16x32_bf16(af[mt], bf_[nt], acc[mt][nt], 0, 0, 0);
  }
  #pragma unroll
  for (int mt = 0; mt < 4; mt++) {
    #pragma unroll
    for (int nt = 0; nt < 4; nt++) {
      #pragma unroll
      for (int i = 0; i < 4; i++) {
        const int row = m0 + wm * 64 + mt * 16 + quad * 4 + i;
        const int col = n0 + wn * 64 + nt * 16 + r;
        const float v = acc[mt][nt][i];
        if constexpr (MODE == 2) {
          ((float*)Y)[(size_t)row * 384 + col] = v + bias[col];
        } else if constexpr (MODE == 0) {
          ((ushort_t*)Y)[(size_t)row * 384 + col] = f2bf(v);
        } else {
          const int bb = row / 784, tt = row % 784;
          ((ushort_t*)Y)[((size_t)bb * 384 + col) * 784 + tt] = f2bf(v);
        }
      }
    }
  }
}

// ---------- Kernel 5: premix res_attn with w_fuse[:,6:12] at source res ----
// Z[b][o][s][t] = sum_c wf2[o][c] * ra[b][c][s][t]   (f32, 196x784 planes)
__global__ __launch_bounds__(256) void k_premix(
    const float* __restrict__ ra, const float* __restrict__ w_fuse,
    float* __restrict__ Z)
{
  const int NP = 196 * 784 / 4;             // float4 chunks per plane = 38416
  const int idx = blockIdx.x * 256 + threadIdx.x;
  if (idx >= 8 * NP) return;
  const int b = idx / NP, st = idx % NP;
  const f32x4* rb = (const f32x4*)(ra + (size_t)b * 6 * 153664) + st;
  f32x4 v[6];
  #pragma unroll
  for (int c = 0; c < 6; c++) v[c] = rb[(size_t)c * NP];
  f32x4* zb = (f32x4*)(Z + (size_t)b * 6 * 153664) + st;
  #pragma unroll
  for (int o = 0; o < 6; o++) {
    f32x4 acc = {};
    #pragma unroll
    for (int c = 0; c < 6; c++) acc += uload(w_fuse + o * 12 + 6 + c) * v[c];
    zb[(size_t)o * NP] = acc;
  }
}

// ---------- Kernel 6: fused flash attention (QK^T + head-mix + res + softmax
//            + PV), scores never leave registers/LDS -------------------------
// Grid (49, 8): block owns 16 query rows (l0..l0+15) of one batch.
// 4 waves split the T=784 key range round-robin over 32-wide tiles; online
// softmax with per-wave deferred max (THR=8); cross-wave merge through LDS.
// __launch_bounds__(256, 1): live set ~220 VGPR (accp 96 + accs 48 + srow 24
// + misc); demanding 2 wg/CU (round 2) made the allocator cap at 128 and
// spill ~290 MB/dispatch to scratch. Cap 512, let HW co-schedule if <=256.
__global__ __launch_bounds__(256, 1) void k_flash(
    const ushort_t* __restrict__ Qb, const ushort_t* __restrict__ Kb,
    const ushort_t* __restrict__ Vt, const float* __restrict__ Z,
    const float* __restrict__ w_fuse, const float* __restrict__ b_fuse,
    ushort_t* __restrict__ O)
{
  const int tid = threadIdx.x, w = tid >> 6, lane = tid & 63;
  const int quad = lane >> 4, r = lane & 15;
  const int b  = blockIdx.y;
  const int l0 = blockIdx.x * 16;

  __shared__ ushort_t Qs[16][424];          // stride 424 elems = 212 dw (20 mod 32)
  __shared__ ushort_t Pl[4][16][40];        // per-wave P tile, m97-style pad
  __shared__ float accbuf[4][16][64];
  __shared__ float sbuf[4][16];
  __shared__ float wmbuf[4][6];

  // stage Q tile: 16 rows x 384 bf16 = 768 8-elem chunks, 3 per thread
  #pragma unroll
  for (int c = 0; c < 3; c++) {
    const int idx = c * 256 + tid;
    const int row = idx / 48, col8 = idx % 48;
    *(uint4*)&Qs[row][col8 * 8] =
        *(const uint4*)(Qb + ((size_t)(b * 784 + l0 + row)) * 384 + col8 * 8);
  }
  __syncthreads();

  // fuse weights (scale folded) into SGPRs
  float wfs[6][6], bfu[6];
  #pragma unroll
  for (int o = 0; o < 6; o++) {
    bfu[o] = uload(b_fuse + o);
    #pragma unroll
    for (int h = 0; h < 6; h++)
      wfs[o][h] = uload(w_fuse + o * 12 + h) * 0.05103103630798288f; // 384^-0.5
  }

  // bilinear constants for this lane's 4 output rows (l = l0 + quad*4 + i)
  int p00a[4], p01a[4], p10a[4];
  float fxa[4], fya[4];
  #pragma unroll
  for (int i = 0; i < 4; i++) {
    const int l = l0 + quad * 4 + i;
    const int Y = l / 28, X = l % 28;
    const float cy = fminf(fmaxf((float)Y * 0.5f - 0.25f, 0.f), 13.f);
    const float cx = fminf(fmaxf((float)X * 0.5f - 0.25f, 0.f), 13.f);
    const int y0 = (int)cy, y1 = min(y0 + 1, 13);
    const int x0 = (int)cx, x1 = min(x0 + 1, 13);
    fya[i] = cy - (float)y0;
    fxa[i] = cx - (float)x0;
    p00a[i] = (y0 * 14 + x0) * 784;
    p01a[i] = (y0 * 14 + x1) * 784;
    p10a[i] = (y1 * 14 + x0) * 784;
  }

  f32x4 accp[6][4] = {};                    // PV accumulators [o][nt]
  float srow[6][4] = {};                    // per-row exp sums [o][i]
  float mo[6];
  #pragma unroll
  for (int o = 0; o < 6; o++) mo[o] = -1e30f;

  for (int tt = w; tt < 25; tt += 4) {      // wave-private t-tiles (32 wide)
    const int t0 = tt * 32;
    const int nj = (t0 + 32 <= 784) ? 2 : 1; // tile 24 is 16 wide

    // ---- QK^T for all 6 heads (A from LDS, B direct from L2-hot Kb) ----
    f32x4 accs[6][2] = {};
    #pragma unroll
    for (int j = 0; j < 2; j++) {
      if (j < nj) {
        const ushort_t* kp = Kb + ((size_t)(b * 784 + t0 + j * 16 + r)) * 384;
        #pragma unroll
        for (int h = 0; h < 6; h++) {
          const bf16x8 a0 = *(const bf16x8*)&Qs[r][h * 64 + quad * 8];
          const bf16x8 a1 = *(const bf16x8*)&Qs[r][h * 64 + 32 + quad * 8];
          accs[h][j] = __builtin_amdgcn_mfma_f32_16x16x32_bf16(
              a0, ld_frag(kp + h * 64 + quad * 8),      accs[h][j], 0, 0, 0);
          accs[h][j] = __builtin_amdgcn_mfma_f32_16x16x32_bf16(
              a1, ld_frag(kp + h * 64 + 32 + quad * 8), accs[h][j], 0, 0, 0);
        }
      }
    }

    // ---- per output head: mix + res bilinear + online softmax + PV ----
    #pragma unroll
    for (int o = 0; o < 6; o++) {
      const float* zo = Z + ((size_t)(b * 6 + o)) * 153664;
      float f[2][4];
      #pragma unroll
      for (int j = 0; j < 2; j++) {
        if (j < nj) {
          const int t = t0 + j * 16 + r;
          #pragma unroll
          for (int i = 0; i < 4; i++) {
            float v = bfu[o];
            #pragma unroll
            for (int h = 0; h < 6; h++) v += wfs[o][h] * accs[h][j][i];
            const float z00 = zo[p00a[i] + t];
            const float z01 = zo[p01a[i] + t];
            const float z10 = zo[p10a[i] + t];
            const float z11 = zo[p10a[i] + p01a[i] - p00a[i] + t];
            const float r0 = z00 + fxa[i] * (z01 - z00);
            const float r1 = z10 + fxa[i] * (z11 - z10);
            f[j][i] = v + r0 + fya[i] * (r1 - r0);
          }
        } else {
          #pragma unroll
          for (int i = 0; i < 4; i++) f[j][i] = -1e30f;
        }
      }
      // wave max (all 64 lanes: per-wave m is valid since rows share m,
      // per-row normalization restored by srow)
      float mx = fmaxf(fmaxf(fmaxf(f[0][0], f[0][1]), fmaxf(f[0][2], f[0][3])),
                       fmaxf(fmaxf(f[1][0], f[1][1]), fmaxf(f[1][2], f[1][3])));
      #pragma unroll
      for (int off = 32; off >= 1; off >>= 1)
        mx = fmaxf(mx, __shfl_xor(mx, off));
      if (mx > mo[o] + 8.f) {               // deferred-max rescale (THR=8)
        const float sc = __expf(mo[o] - mx);
        mo[o] = mx;
        #pragma unroll
        for (int nt = 0; nt < 4; nt++) accp[o][nt] *= sc;
        #pragma unroll
        for (int i = 0; i < 4; i++) srow[o][i] *= sc;
      }
      #pragma unroll
      for (int j = 0; j < 2; j++) {
        #pragma unroll
        for (int i = 0; i < 4; i++) {
          const float p = __expf(f[j][i] - mo[o]);   // <= e^8; tail j -> 0
          srow[o][i] += p;
          Pl[w][quad * 4 + i][j * 16 + r] = f2bf(p);
        }
      }
      // PV: A = P from this wave's LDS tile, B = V direct (L2-hot).
      // Tail (t0=768): quad0 k=768..775, quad1 k=776..783 (clamp must allow
      // 776! 776+8=784 stays in-row); quads 2,3 have P==0, clamp them to 776.
      const bf16x8 pa = *(const bf16x8*)&Pl[w][r][quad * 8];
      const int vt0 = min(t0 + quad * 8, 776);
      const ushort_t* vp = Vt + ((size_t)(b * 384 + o * 64 + r)) * 784 + vt0;
      #pragma unroll
      for (int nt = 0; nt < 4; nt++)
        accp[o][nt] = __builtin_amdgcn_mfma_f32_16x16x32_bf16(
            pa, ld_frag(vp + (size_t)nt * 16 * 784), accp[o][nt], 0, 0, 0);
    }
  }

  // ---- epilogue: reduce row sums over the 16 columns lanes ----
  #pragma unroll
  for (int o = 0; o < 6; o++)
    #pragma unroll
    for (int i = 0; i < 4; i++)
      #pragma unroll
      for (int m = 1; m <= 8; m <<= 1)
        srow[o][i] += __shfl_xor(srow[o][i], m);

  if (lane == 0) {
    #pragma unroll
    for (int o = 0; o < 6; o++) wmbuf[w][o] = mo[o];
  }
  __syncthreads();

  const int orow = tid >> 4, ocol = (tid & 15) << 2;
  #pragma unroll
  for (int o = 0; o < 6; o++) {
    const float M = fmaxf(fmaxf(wmbuf[0][o], wmbuf[1][o]),
                          fmaxf(wmbuf[2][o], wmbuf[3][o]));
    const float ew = __expf(mo[o] - M);
    #pragma unroll
    for (int nt = 0; nt < 4; nt++)
      #pragma unroll
      for (int i = 0; i < 4; i++)
        accbuf[w][quad * 4 + i][nt * 16 + r] = accp[o][nt][i] * ew;
    if (r == 0) {
      #pragma unroll
      for (int i = 0; i < 4; i++) sbuf[w][quad * 4 + i] = srow[o][i] * ew;
    }
    __syncthreads();
    const float st = sbuf[0][orow] + sbuf[1][orow] + sbuf[2][orow] + sbuf[3][orow];
    const float inv = 1.f / st;
    ushort_t pk[4];
    #pragma unroll
    for (int e = 0; e < 4; e++) {
      const float v = (accbuf[0][orow][ocol + e] + accbuf[1][orow][ocol + e]
                     + accbuf[2][orow][ocol + e] + accbuf[3][orow][ocol + e]) * inv;
      pk[e] = f2bf(v);
    }
    uint2 w2;
    w2.x = (uint)pk[0] | ((uint)pk[1] << 16);
    w2.y = (uint)pk[2] | ((uint)pk[3] << 16);
    *(uint2*)(O + ((size_t)(b * 784) + l0 + orow) * 384 + o * 64 + ocol) = w2;
    __syncthreads();
  }
}

// ---------- host launcher ----------
extern "C" void kernel_launch(void* const* d_in, const int* in_sizes, int n_in,
                              void* d_out, int out_size, void* d_ws, size_t ws_size,
                              hipStream_t stream)
{
  const float* x        = (const float*)d_in[0];
  const float* res_attn = (const float*)d_in[1];
  const float* conv_w   = (const float*)d_in[2];
  const float* ln_g     = (const float*)d_in[3];
  const float* ln_b     = (const float*)d_in[4];
  const float* wq       = (const float*)d_in[5];
  const float* wk       = (const float*)d_in[6];
  const float* wv       = (const float*)d_in[7];
  const float* w_proj   = (const float*)d_in[8];
  const float* b_proj   = (const float*)d_in[9];
  const float* w_fuse   = (const float*)d_in[10];
  const float* b_fuse   = (const float*)d_in[11];
  float* out = (float*)d_out;

  // ws layout (bf16 elements), ~60 MB total
  const size_t NE = (size_t)8 * 784 * 384;      // 2,408,448
  const size_t NW = 147456;
  ushort_t* q_ln_b = (ushort_t*)d_ws;
  ushort_t* kv_b   = q_ln_b + NE;
  ushort_t* Qb     = kv_b + NE;
  ushort_t* Kb     = Qb + NE;
  ushort_t* Vt     = Kb + NE;   // (b, 384, 784)
  ushort_t* Opre   = Vt + NE;
  ushort_t* wqb    = Opre + NE;
  ushort_t* wkb    = wqb + NW;
  ushort_t* wvb    = wkb + NW;
  ushort_t* wpb    = wvb + NW;
  float*    Z      = (float*)(wpb + NW);  // premixed res (b,6,196,784) f32, 16B-aligned

  k_premix<<<dim3(1201),   dim3(256), 0, stream>>>(res_attn, w_fuse, Z);
  k_convln<<<dim3(8 * 784), dim3(384), 0, stream>>>(x, conv_w, ln_g, ln_b, q_ln_b);
  k_pool  <<<dim3(9408),    dim3(256), 0, stream>>>(x, kv_b);
  k_wcvt  <<<dim3(576),     dim3(256), 0, stream>>>(wq, wk, wv, w_proj, wqb, wkb, wvb, wpb);

  k_gemm<0><<<dim3(3, 49), dim3(256), 0, stream>>>(q_ln_b, wqb, nullptr, Qb);
  k_gemm<0><<<dim3(3, 49), dim3(256), 0, stream>>>(kv_b,   wkb, nullptr, Kb);
  k_gemm<1><<<dim3(3, 49), dim3(256), 0, stream>>>(kv_b,   wvb, nullptr, Vt);

  k_flash<<<dim3(49, 8), dim3(256), 0, stream>>>(Qb, Kb, Vt, Z, w_fuse, b_fuse, Opre);

  k_gemm<2><<<dim3(3, 49), dim3(256), 0, stream>>>(Opre, wpb, b_proj, out);
}

// Round 4
// 411.275 us; speedup vs baseline: 1.2308x; 1.2308x over previous
//
#include <hip/hip_runtime.h>

typedef unsigned int uint;
typedef unsigned short ushort_t;
typedef short bf16x8 __attribute__((ext_vector_type(8)));
typedef float f32x4 __attribute__((ext_vector_type(4)));

// ---------- bf16 helpers ----------
__device__ __forceinline__ ushort_t f2bf(float f) {
  uint u = __builtin_bit_cast(uint, f);
  u += 0x7fffu + ((u >> 16) & 1u);
  return (ushort_t)(u >> 16);
}
__device__ __forceinline__ float bf2f(ushort_t s) {
  return __builtin_bit_cast(float, (uint)s << 16);
}
__device__ __forceinline__ bf16x8 ld_frag(const ushort_t* p) {
  return __builtin_bit_cast(bf16x8, *(const uint4*)p);
}
// force a wave-uniform load into an SGPR (keeps the fuse weights off VGPRs)
__device__ __forceinline__ float uload(const float* p) {
  return __builtin_bit_cast(float,
      __builtin_amdgcn_readfirstlane(__builtin_bit_cast(int, *p)));
}

// ---------- Kernel 1: depthwise conv 3x3 s2 p1 + LayerNorm -> bf16 ----------
__global__ __launch_bounds__(384) void k_convln(
    const float* __restrict__ x, const float* __restrict__ wc,
    const float* __restrict__ g, const float* __restrict__ bb,
    ushort_t* __restrict__ qout)
{
  const int b  = blockIdx.x / 784;
  const int t  = blockIdx.x % 784;
  const int oy = t / 28, ox = t % 28;
  const int c  = threadIdx.x;
  const float* xb = x + (size_t)b * 3136 * 384 + c;
  float acc = 0.f;
  #pragma unroll
  for (int ky = 0; ky < 3; ky++) {
    const int iy = 2 * oy - 1 + ky;
    if (iy < 0 || iy >= 56) continue;
    #pragma unroll
    for (int kx = 0; kx < 3; kx++) {
      const int ix = 2 * ox - 1 + kx;
      if (ix < 0 || ix >= 56) continue;
      acc += wc[c * 9 + ky * 3 + kx] * xb[(size_t)(iy * 56 + ix) * 384];
    }
  }
  float s = acc, s2 = acc * acc;
  #pragma unroll
  for (int off = 32; off >= 1; off >>= 1) {
    s  += __shfl_xor(s,  off);
    s2 += __shfl_xor(s2, off);
  }
  __shared__ float ps[6], ps2[6];
  if ((c & 63) == 0) { ps[c >> 6] = s; ps2[c >> 6] = s2; }
  __syncthreads();
  float S = 0.f, S2 = 0.f;
  #pragma unroll
  for (int i = 0; i < 6; i++) { S += ps[i]; S2 += ps2[i]; }
  const float mu  = S * (1.f / 384.f);
  const float var = S2 * (1.f / 384.f) - mu * mu;
  const float inv = rsqrtf(var + 1e-5f);
  qout[((size_t)b * 784 + t) * 384 + c] = f2bf((acc - mu) * inv * g[c] + bb[c]);
}

// ---------- Kernel 2: 2x2 average pool -> bf16 ----------
__global__ __launch_bounds__(256) void k_pool(
    const float* __restrict__ x, ushort_t* __restrict__ kvout)
{
  const int idx = blockIdx.x * 256 + threadIdx.x;
  const int c = idx % 384;
  const int t = (idx / 384) % 784;
  const int b = idx / (384 * 784);
  const int ty = t / 28, tx = t % 28;
  const float* xb = x + (size_t)b * 3136 * 384 + c;
  const int r0 = (2 * ty) * 56 + 2 * tx;
  const float v = xb[(size_t)r0 * 384] + xb[(size_t)(r0 + 1) * 384]
                + xb[(size_t)(r0 + 56) * 384] + xb[(size_t)(r0 + 57) * 384];
  kvout[idx] = f2bf(v * 0.25f);
}

// ---------- Kernel 3: weights f32 -> bf16 ----------
__global__ __launch_bounds__(256) void k_wcvt(
    const float* __restrict__ a, const float* __restrict__ b,
    const float* __restrict__ c, const float* __restrict__ d,
    ushort_t* __restrict__ oa, ushort_t* __restrict__ ob,
    ushort_t* __restrict__ oc, ushort_t* __restrict__ od)
{
  const int i = blockIdx.x * 256 + threadIdx.x;
  if (i < 147456) {
    oa[i] = f2bf(a[i]); ob[i] = f2bf(b[i]);
    oc[i] = f2bf(c[i]); od[i] = f2bf(d[i]);
  }
}

// ---------- Kernel 4: dense MFMA GEMM, M=6272 N=384 K=384 ----------
// Y[m,n] = sum_k X[m,k]*W[n,k]. 128x128 tile, 4 waves (2x2), 4x4 16x16 tiles.
// MODE 0: bf16 row-major out; MODE 1: bf16 transposed (b,384,784) out (for V);
// MODE 2: f32 +bias out.
template<int MODE>
__global__ __launch_bounds__(256) void k_gemm(
    const ushort_t* __restrict__ X, const ushort_t* __restrict__ W,
    const float* __restrict__ bias, void* __restrict__ Y)
{
  __shared__ ushort_t As[128][40];  // pad 32->40: row stride 20 words (2-way, free)
  __shared__ ushort_t Bs[128][40];
  const int tid = threadIdx.x, w = tid >> 6, lane = tid & 63;
  const int quad = lane >> 4, r = lane & 15;
  const int m0 = blockIdx.y * 128, n0 = blockIdx.x * 128;
  const int wm = w >> 1, wn = w & 1;
  const int lr = tid >> 2, lc = (tid & 3) << 3;
  const ushort_t* xp = X + (size_t)(m0 + lr) * 384 + lc;
  const ushort_t* wp = W + (size_t)(n0 + lr) * 384 + lc;
  f32x4 acc[4][4] = {};
  for (int k0 = 0; k0 < 384; k0 += 32) {
    __syncthreads();
    *(uint4*)&As[lr][lc]      = *(const uint4*)(xp + k0);
    *(uint4*)&As[lr + 64][lc] = *(const uint4*)(xp + (size_t)64 * 384 + k0);
    *(uint4*)&Bs[lr][lc]      = *(const uint4*)(wp + k0);
    *(uint4*)&Bs[lr + 64][lc] = *(const uint4*)(wp + (size_t)64 * 384 + k0);
    __syncthreads();
    bf16x8 af[4], bf_[4];
    #pragma unroll
    for (int mt = 0; mt < 4; mt++) af[mt]  = *(const bf16x8*)&As[wm * 64 + mt * 16 + r][quad * 8];
    #pragma unroll
    for (int nt = 0; nt < 4; nt++) bf_[nt] = *(const bf16x8*)&Bs[wn * 64 + nt * 16 + r][quad * 8];
    #pragma unroll
    for (int mt = 0; mt < 4; mt++)
      #pragma unroll
      for (int nt = 0; nt < 4; nt++)
        acc[mt][nt] = __builtin_amdgcn_mfma_f32_16x16x32_bf16(af[mt], bf_[nt], acc[mt][nt], 0, 0, 0);
  }
  #pragma unroll
  for (int mt = 0; mt < 4; mt++) {
    #pragma unroll
    for (int nt = 0; nt < 4; nt++) {
      #pragma unroll
      for (int i = 0; i < 4; i++) {
        const int row = m0 + wm * 64 + mt * 16 + quad * 4 + i;
        const int col = n0 + wn * 64 + nt * 16 + r;
        const float v = acc[mt][nt][i];
        if constexpr (MODE == 2) {
          ((float*)Y)[(size_t)row * 384 + col] = v + bias[col];
        } else if constexpr (MODE == 0) {
          ((ushort_t*)Y)[(size_t)row * 384 + col] = f2bf(v);
        } else {
          const int bb = row / 784, tt = row % 784;
          ((ushort_t*)Y)[((size_t)bb * 384 + col) * 784 + tt] = f2bf(v);
        }
      }
    }
  }
}

// ---------- Kernel 5: premix res_attn with w_fuse[:,6:12] at source res ----
// Z[b][o][s][t] = sum_c wf2[o][c] * ra[b][c][s][t]   (f32, 196x784 planes)
__global__ __launch_bounds__(256) void k_premix(
    const float* __restrict__ ra, const float* __restrict__ w_fuse,
    float* __restrict__ Z)
{
  const int NP = 196 * 784 / 4;             // float4 chunks per plane = 38416
  const int idx = blockIdx.x * 256 + threadIdx.x;
  if (idx >= 8 * NP) return;
  const int b = idx / NP, st = idx % NP;
  const f32x4* rb = (const f32x4*)(ra + (size_t)b * 6 * 153664) + st;
  f32x4 v[6];
  #pragma unroll
  for (int c = 0; c < 6; c++) v[c] = rb[(size_t)c * NP];
  f32x4* zb = (f32x4*)(Z + (size_t)b * 6 * 153664) + st;
  #pragma unroll
  for (int o = 0; o < 6; o++) {
    f32x4 acc = {};
    #pragma unroll
    for (int c = 0; c < 6; c++) acc += uload(w_fuse + o * 12 + 6 + c) * v[c];
    zb[(size_t)o * NP] = acc;
  }
}

// ---------- Kernel 6: fused flash attention, o-split --------------------------
// Flat grid 784 blocks: bid&7 = batch (XCD-affine), then 49 l-tiles x 2 o-halves.
// Block owns 16 query rows and 3 OUTPUT heads; QK^T for all 6 input heads is
// recomputed in both halves (mix couples them; MFMA is cheap, K is L2-hot).
// Progressive head-mix (fmix += wfs*acc2 per h) keeps peak VGPR ~160 so we get
// >=2 (target 3) waves/SIMD; round-3 version held accs[6]+accp[6] = 256 VGPR
// -> 2 waves/SIMD on a 392-block grid = 9% occupancy, latency-bound (303 us).
__global__ __launch_bounds__(256, 1) void k_flash(
    const ushort_t* __restrict__ Qb, const ushort_t* __restrict__ Kb,
    const ushort_t* __restrict__ Vt, const float* __restrict__ Z,
    const float* __restrict__ w_fuse, const float* __restrict__ b_fuse,
    ushort_t* __restrict__ O)
{
  const int tid = threadIdx.x, w = tid >> 6, lane = tid & 63;
  const int quad = lane >> 4, r = lane & 15;
  const int bid = blockIdx.x;
  const int b   = bid & 7;                  // XCD-affine batch mapping
  const int rr  = bid >> 3;                 // 0..97
  const int l0  = (rr % 49) * 16;
  const int zb  = (rr / 49) * 3;            // output-head base: 0 or 3

  __shared__ ushort_t Qs[16][424];          // stride 424 elems = 212 dw (20 mod 32)
  __shared__ ushort_t Pl[4][16][40];        // per-wave P tile, padded
  __shared__ float accbuf[4][16][64];
  __shared__ float sbuf[4][16];
  __shared__ float wmbuf[4][3];

  // stage Q tile: 16 rows x 384 bf16 = 768 8-elem chunks, 3 per thread
  #pragma unroll
  for (int c = 0; c < 3; c++) {
    const int idx = c * 256 + tid;
    const int row = idx / 48, col8 = idx % 48;
    *(uint4*)&Qs[row][col8 * 8] =
        *(const uint4*)(Qb + ((size_t)(b * 784 + l0 + row)) * 384 + col8 * 8);
  }
  __syncthreads();

  // fuse weights (scale folded) into SGPRs -- only this half's 3 output heads
  float wfs[3][6], bfu[3];
  #pragma unroll
  for (int o = 0; o < 3; o++) {
    bfu[o] = uload(b_fuse + zb + o);
    #pragma unroll
    for (int h = 0; h < 6; h++)
      wfs[o][h] = uload(w_fuse + (zb + o) * 12 + h) * 0.05103103630798288f;
  }

  // bilinear constants for this lane's 4 output rows (l = l0 + quad*4 + i)
  int p00a[4], p01a[4], p10a[4];
  float fxa[4], fya[4];
  #pragma unroll
  for (int i = 0; i < 4; i++) {
    const int l = l0 + quad * 4 + i;
    const int Y = l / 28, X = l % 28;
    const float cy = fminf(fmaxf((float)Y * 0.5f - 0.25f, 0.f), 13.f);
    const float cx = fminf(fmaxf((float)X * 0.5f - 0.25f, 0.f), 13.f);
    const int y0 = (int)cy, y1 = min(y0 + 1, 13);
    const int x0 = (int)cx, x1 = min(x0 + 1, 13);
    fya[i] = cy - (float)y0;
    fxa[i] = cx - (float)x0;
    p00a[i] = (y0 * 14 + x0) * 784;
    p01a[i] = (y0 * 14 + x1) * 784;
    p10a[i] = (y1 * 14 + x0) * 784;
  }

  f32x4 accp[3][4] = {};                    // PV accumulators [o][nt]
  float srow[3][4] = {};                    // per-row exp sums [o][i]
  float mo[3];
  #pragma unroll
  for (int o = 0; o < 3; o++) mo[o] = -1e30f;

  for (int tt = w; tt < 25; tt += 4) {      // wave-private t-tiles (32 wide)
    const int t0 = tt * 32;
    const int nj = (t0 + 32 <= 784) ? 2 : 1; // tile 24 is 16 wide

    // ---- QK^T all 6 input heads, folded into fmix progressively ----
    float fmix[3][2][4] = {};
    #pragma unroll
    for (int h = 0; h < 6; h++) {
      f32x4 acc2[2] = {};
      #pragma unroll
      for (int j = 0; j < 2; j++) {
        if (j < nj) {
          const ushort_t* kp = Kb + ((size_t)(b * 784 + t0 + j * 16 + r)) * 384 + h * 64;
          const bf16x8 a0 = *(const bf16x8*)&Qs[r][h * 64 + quad * 8];
          const bf16x8 a1 = *(const bf16x8*)&Qs[r][h * 64 + 32 + quad * 8];
          acc2[j] = __builtin_amdgcn_mfma_f32_16x16x32_bf16(
              a0, ld_frag(kp + quad * 8),      acc2[j], 0, 0, 0);
          acc2[j] = __builtin_amdgcn_mfma_f32_16x16x32_bf16(
              a1, ld_frag(kp + 32 + quad * 8), acc2[j], 0, 0, 0);
        }
      }
      #pragma unroll
      for (int o = 0; o < 3; o++) {
        const float wf = wfs[o][h];
        #pragma unroll
        for (int j = 0; j < 2; j++)
          #pragma unroll
          for (int i = 0; i < 4; i++)
            fmix[o][j][i] += wf * acc2[j][i];
      }
    }

    // ---- per output head: +bias +res bilinear, online softmax, PV ----
    #pragma unroll
    for (int o = 0; o < 3; o++) {
      const float* zo = Z + ((size_t)(b * 6 + zb + o)) * 153664;
      float f[2][4];
      #pragma unroll
      for (int j = 0; j < 2; j++) {
        if (j < nj) {
          const int t = t0 + j * 16 + r;
          #pragma unroll
          for (int i = 0; i < 4; i++) {
            const float z00 = zo[p00a[i] + t];
            const float z01 = zo[p01a[i] + t];
            const float z10 = zo[p10a[i] + t];
            const float z11 = zo[p10a[i] + p01a[i] - p00a[i] + t];
            const float r0 = z00 + fxa[i] * (z01 - z00);
            const float r1 = z10 + fxa[i] * (z11 - z10);
            f[j][i] = fmix[o][j][i] + bfu[o] + r0 + fya[i] * (r1 - r0);
          }
        } else {
          #pragma unroll
          for (int i = 0; i < 4; i++) f[j][i] = -1e30f;
        }
      }
      // wave max (per-wave m valid: rows share m, normalization via srow)
      float mx = fmaxf(fmaxf(fmaxf(f[0][0], f[0][1]), fmaxf(f[0][2], f[0][3])),
                       fmaxf(fmaxf(f[1][0], f[1][1]), fmaxf(f[1][2], f[1][3])));
      #pragma unroll
      for (int off = 32; off >= 1; off >>= 1)
        mx = fmaxf(mx, __shfl_xor(mx, off));
      if (mx > mo[o] + 8.f) {               // deferred-max rescale (THR=8)
        const float sc = __expf(mo[o] - mx);
        mo[o] = mx;
        #pragma unroll
        for (int nt = 0; nt < 4; nt++) accp[o][nt] *= sc;
        #pragma unroll
        for (int i = 0; i < 4; i++) srow[o][i] *= sc;
      }
      #pragma unroll
      for (int j = 0; j < 2; j++) {
        #pragma unroll
        for (int i = 0; i < 4; i++) {
          const float p = __expf(f[j][i] - mo[o]);   // <= e^8; tail j -> 0
          srow[o][i] += p;
          Pl[w][quad * 4 + i][j * 16 + r] = f2bf(p);
        }
      }
      // PV: A = P from this wave's LDS tile, B = V direct (L2-hot).
      // Tail (t0=768): quad0 k=768..775, quad1 k=776..783 (clamp allows 776;
      // 776+8=784 in-row); quads 2,3 have P==0, clamped to 776.
      const bf16x8 pa = *(const bf16x8*)&Pl[w][r][quad * 8];
      const int vt0 = min(t0 + quad * 8, 776);
      const ushort_t* vp = Vt + ((size_t)(b * 384 + (zb + o) * 64 + r)) * 784 + vt0;
      #pragma unroll
      for (int nt = 0; nt < 4; nt++)
        accp[o][nt] = __builtin_amdgcn_mfma_f32_16x16x32_bf16(
            pa, ld_frag(vp + (size_t)nt * 16 * 784), accp[o][nt], 0, 0, 0);
    }
  }

  // ---- epilogue: reduce row sums over the 16 column lanes ----
  #pragma unroll
  for (int o = 0; o < 3; o++)
    #pragma unroll
    for (int i = 0; i < 4; i++)
      #pragma unroll
      for (int m = 1; m <= 8; m <<= 1)
        srow[o][i] += __shfl_xor(srow[o][i], m);

  if (lane == 0) {
    #pragma unroll
    for (int o = 0; o < 3; o++) wmbuf[w][o] = mo[o];
  }
  __syncthreads();

  const int orow = tid >> 4, ocol = (tid & 15) << 2;
  #pragma unroll
  for (int o = 0; o < 3; o++) {
    const float M = fmaxf(fmaxf(wmbuf[0][o], wmbuf[1][o]),
                          fmaxf(wmbuf[2][o], wmbuf[3][o]));
    const float ew = __expf(mo[o] - M);
    #pragma unroll
    for (int nt = 0; nt < 4; nt++)
      #pragma unroll
      for (int i = 0; i < 4; i++)
        accbuf[w][quad * 4 + i][nt * 16 + r] = accp[o][nt][i] * ew;
    if (r == 0) {
      #pragma unroll
      for (int i = 0; i < 4; i++) sbuf[w][quad * 4 + i] = srow[o][i] * ew;
    }
    __syncthreads();
    const float st = sbuf[0][orow] + sbuf[1][orow] + sbuf[2][orow] + sbuf[3][orow];
    const float inv = 1.f / st;
    ushort_t pk[4];
    #pragma unroll
    for (int e = 0; e < 4; e++) {
      const float v = (accbuf[0][orow][ocol + e] + accbuf[1][orow][ocol + e]
                     + accbuf[2][orow][ocol + e] + accbuf[3][orow][ocol + e]) * inv;
      pk[e] = f2bf(v);
    }
    uint2 w2;
    w2.x = (uint)pk[0] | ((uint)pk[1] << 16);
    w2.y = (uint)pk[2] | ((uint)pk[3] << 16);
    *(uint2*)(O + ((size_t)(b * 784) + l0 + orow) * 384 + (zb + o) * 64 + ocol) = w2;
    __syncthreads();
  }
}

// ---------- host launcher ----------
extern "C" void kernel_launch(void* const* d_in, const int* in_sizes, int n_in,
                              void* d_out, int out_size, void* d_ws, size_t ws_size,
                              hipStream_t stream)
{
  const float* x        = (const float*)d_in[0];
  const float* res_attn = (const float*)d_in[1];
  const float* conv_w   = (const float*)d_in[2];
  const float* ln_g     = (const float*)d_in[3];
  const float* ln_b     = (const float*)d_in[4];
  const float* wq       = (const float*)d_in[5];
  const float* wk       = (const float*)d_in[6];
  const float* wv       = (const float*)d_in[7];
  const float* w_proj   = (const float*)d_in[8];
  const float* b_proj   = (const float*)d_in[9];
  const float* w_fuse   = (const float*)d_in[10];
  const float* b_fuse   = (const float*)d_in[11];
  float* out = (float*)d_out;

  // ws layout (bf16 elements), ~60 MB total
  const size_t NE = (size_t)8 * 784 * 384;      // 2,408,448
  const size_t NW = 147456;
  ushort_t* q_ln_b = (ushort_t*)d_ws;
  ushort_t* kv_b   = q_ln_b + NE;
  ushort_t* Qb     = kv_b + NE;
  ushort_t* Kb     = Qb + NE;
  ushort_t* Vt     = Kb + NE;   // (b, 384, 784)
  ushort_t* Opre   = Vt + NE;
  ushort_t* wqb    = Opre + NE;
  ushort_t* wkb    = wqb + NW;
  ushort_t* wvb    = wkb + NW;
  ushort_t* wpb    = wvb + NW;
  float*    Z      = (float*)(wpb + NW);  // premixed res (b,6,196,784) f32, 16B-aligned

  k_premix<<<dim3(1201),   dim3(256), 0, stream>>>(res_attn, w_fuse, Z);
  k_convln<<<dim3(8 * 784), dim3(384), 0, stream>>>(x, conv_w, ln_g, ln_b, q_ln_b);
  k_pool  <<<dim3(9408),    dim3(256), 0, stream>>>(x, kv_b);
  k_wcvt  <<<dim3(576),     dim3(256), 0, stream>>>(wq, wk, wv, w_proj, wqb, wkb, wvb, wpb);

  k_gemm<0><<<dim3(3, 49), dim3(256), 0, stream>>>(q_ln_b, wqb, nullptr, Qb);
  k_gemm<0><<<dim3(3, 49), dim3(256), 0, stream>>>(kv_b,   wkb, nullptr, Kb);
  k_gemm<1><<<dim3(3, 49), dim3(256), 0, stream>>>(kv_b,   wvb, nullptr, Vt);

  k_flash<<<dim3(784), dim3(256), 0, stream>>>(Qb, Kb, Vt, Z, w_fuse, b_fuse, Opre);

  k_gemm<2><<<dim3(3, 49), dim3(256), 0, stream>>>(Opre, wpb, b_proj, out);
}

// Round 5
// 397.648 us; speedup vs baseline: 1.2730x; 1.0343x over previous
//
#include <hip/hip_runtime.h>

typedef unsigned int uint;
typedef unsigned short ushort_t;
typedef short bf16x8 __attribute__((ext_vector_type(8)));
typedef float f32x4 __attribute__((ext_vector_type(4)));

// ---------- bf16 helpers ----------
__device__ __forceinline__ ushort_t f2bf(float f) {
  uint u = __builtin_bit_cast(uint, f);
  u += 0x7fffu + ((u >> 16) & 1u);
  return (ushort_t)(u >> 16);
}
__device__ __forceinline__ float bf2f(ushort_t s) {
  return __builtin_bit_cast(float, (uint)s << 16);
}
__device__ __forceinline__ bf16x8 ld_frag(const ushort_t* p) {
  return __builtin_bit_cast(bf16x8, *(const uint4*)p);
}
// wave-uniform load -> SGPR
__device__ __forceinline__ float uload(const float* p) {
  return __builtin_bit_cast(float,
      __builtin_amdgcn_readfirstlane(__builtin_bit_cast(int, *p)));
}

// ---------- Kernel 1: depthwise conv 3x3 s2 p1 + LayerNorm -> bf16 ----------
__global__ __launch_bounds__(384) void k_convln(
    const float* __restrict__ x, const float* __restrict__ wc,
    const float* __restrict__ g, const float* __restrict__ bb,
    ushort_t* __restrict__ qout)
{
  const int b  = blockIdx.x / 784;
  const int t  = blockIdx.x % 784;
  const int oy = t / 28, ox = t % 28;
  const int c  = threadIdx.x;
  const float* xb = x + (size_t)b * 3136 * 384 + c;
  float acc = 0.f;
  #pragma unroll
  for (int ky = 0; ky < 3; ky++) {
    const int iy = 2 * oy - 1 + ky;
    if (iy < 0 || iy >= 56) continue;
    #pragma unroll
    for (int kx = 0; kx < 3; kx++) {
      const int ix = 2 * ox - 1 + kx;
      if (ix < 0 || ix >= 56) continue;
      acc += wc[c * 9 + ky * 3 + kx] * xb[(size_t)(iy * 56 + ix) * 384];
    }
  }
  float s = acc, s2 = acc * acc;
  #pragma unroll
  for (int off = 32; off >= 1; off >>= 1) {
    s  += __shfl_xor(s,  off);
    s2 += __shfl_xor(s2, off);
  }
  __shared__ float ps[6], ps2[6];
  if ((c & 63) == 0) { ps[c >> 6] = s; ps2[c >> 6] = s2; }
  __syncthreads();
  float S = 0.f, S2 = 0.f;
  #pragma unroll
  for (int i = 0; i < 6; i++) { S += ps[i]; S2 += ps2[i]; }
  const float mu  = S * (1.f / 384.f);
  const float var = S2 * (1.f / 384.f) - mu * mu;
  const float inv = rsqrtf(var + 1e-5f);
  qout[((size_t)b * 784 + t) * 384 + c] = f2bf((acc - mu) * inv * g[c] + bb[c]);
}

// ---------- Kernel 2: 2x2 average pool -> bf16 ----------
__global__ __launch_bounds__(256) void k_pool(
    const float* __restrict__ x, ushort_t* __restrict__ kvout)
{
  const int idx = blockIdx.x * 256 + threadIdx.x;
  const int c = idx % 384;
  const int t = (idx / 384) % 784;
  const int b = idx / (384 * 784);
  const int ty = t / 28, tx = t % 28;
  const float* xb = x + (size_t)b * 3136 * 384 + c;
  const int r0 = (2 * ty) * 56 + 2 * tx;
  const float v = xb[(size_t)r0 * 384] + xb[(size_t)(r0 + 1) * 384]
                + xb[(size_t)(r0 + 56) * 384] + xb[(size_t)(r0 + 57) * 384];
  kvout[idx] = f2bf(v * 0.25f);
}

// ---------- Kernel 3: weights f32 -> bf16 ----------
__global__ __launch_bounds__(256) void k_wcvt(
    const float* __restrict__ a, const float* __restrict__ b,
    const float* __restrict__ c, const float* __restrict__ d,
    ushort_t* __restrict__ oa, ushort_t* __restrict__ ob,
    ushort_t* __restrict__ oc, ushort_t* __restrict__ od)
{
  const int i = blockIdx.x * 256 + threadIdx.x;
  if (i < 147456) {
    oa[i] = f2bf(a[i]); ob[i] = f2bf(b[i]);
    oc[i] = f2bf(c[i]); od[i] = f2bf(d[i]);
  }
}

// ---------- Kernel 4: dense MFMA GEMM, M=6272 N=384 K=384 ----------
template<int MODE>
__global__ __launch_bounds__(256) void k_gemm(
    const ushort_t* __restrict__ X, const ushort_t* __restrict__ W,
    const float* __restrict__ bias, void* __restrict__ Y)
{
  __shared__ ushort_t As[128][40];
  __shared__ ushort_t Bs[128][40];
  const int tid = threadIdx.x, w = tid >> 6, lane = tid & 63;
  const int quad = lane >> 4, r = lane & 15;
  const int m0 = blockIdx.y * 128, n0 = blockIdx.x * 128;
  const int wm = w >> 1, wn = w & 1;
  const int lr = tid >> 2, lc = (tid & 3) << 3;
  const ushort_t* xp = X + (size_t)(m0 + lr) * 384 + lc;
  const ushort_t* wp = W + (size_t)(n0 + lr) * 384 + lc;
  f32x4 acc[4][4] = {};
  for (int k0 = 0; k0 < 384; k0 += 32) {
    __syncthreads();
    *(uint4*)&As[lr][lc]      = *(const uint4*)(xp + k0);
    *(uint4*)&As[lr + 64][lc] = *(const uint4*)(xp + (size_t)64 * 384 + k0);
    *(uint4*)&Bs[lr][lc]      = *(const uint4*)(wp + k0);
    *(uint4*)&Bs[lr + 64][lc] = *(const uint4*)(wp + (size_t)64 * 384 + k0);
    __syncthreads();
    bf16x8 af[4], bf_[4];
    #pragma unroll
    for (int mt = 0; mt < 4; mt++) af[mt]  = *(const bf16x8*)&As[wm * 64 + mt * 16 + r][quad * 8];
    #pragma unroll
    for (int nt = 0; nt < 4; nt++) bf_[nt] = *(const bf16x8*)&Bs[wn * 64 + nt * 16 + r][quad * 8];
    #pragma unroll
    for (int mt = 0; mt < 4; mt++)
      #pragma unroll
      for (int nt = 0; nt < 4; nt++)
        acc[mt][nt] = __builtin_amdgcn_mfma_f32_16x16x32_bf16(af[mt], bf_[nt], acc[mt][nt], 0, 0, 0);
  }
  #pragma unroll
  for (int mt = 0; mt < 4; mt++) {
    #pragma unroll
    for (int nt = 0; nt < 4; nt++) {
      #pragma unroll
      for (int i = 0; i < 4; i++) {
        const int row = m0 + wm * 64 + mt * 16 + quad * 4 + i;
        const int col = n0 + wn * 64 + nt * 16 + r;
        const float v = acc[mt][nt][i];
        if constexpr (MODE == 2) {
          ((float*)Y)[(size_t)row * 384 + col] = v + bias[col];
        } else if constexpr (MODE == 0) {
          ((ushort_t*)Y)[(size_t)row * 384 + col] = f2bf(v);
        } else {
          const int bb = row / 784, tt = row % 784;
          ((ushort_t*)Y)[((size_t)bb * 384 + col) * 784 + tt] = f2bf(v);
        }
      }
    }
  }
}

// ---------- Kernel 5: premix res_attn with w_fuse[:,6:12] at source res ----
__global__ __launch_bounds__(256) void k_premix(
    const float* __restrict__ ra, const float* __restrict__ w_fuse,
    float* __restrict__ Z)
{
  const int NP = 196 * 784 / 4;
  const int idx = blockIdx.x * 256 + threadIdx.x;
  if (idx >= 8 * NP) return;
  const int b = idx / NP, st = idx % NP;
  const f32x4* rb = (const f32x4*)(ra + (size_t)b * 6 * 153664) + st;
  f32x4 v[6];
  #pragma unroll
  for (int c = 0; c < 6; c++) v[c] = rb[(size_t)c * NP];
  f32x4* zb = (f32x4*)(Z + (size_t)b * 6 * 153664) + st;
  #pragma unroll
  for (int o = 0; o < 6; o++) {
    f32x4 acc = {};
    #pragma unroll
    for (int c = 0; c < 6; c++) acc += uload(w_fuse + o * 12 + 6 + c) * v[c];
    zb[(size_t)o * NP] = acc;
  }
}

// ---------- Kernel 6: fused-score GEMM --------------------------------------
// S_f[bo][l][t] = sum_k (wf[o,c(k)]*scale*Q[b,l,k]) * K[b,t,k] + b_fuse[o]
//              + bilerp(Z[b,o], l, t)
// Head-mix folded into A-operand scaling: one K=384 GEMM per (b,o).
// Block: 64 l-rows (4 waves x 16) x 64 t-cols, K staged in LDS (shared by
// all 4 waves; stride 424 elems = 212 dw = 20 mod 32 -> minimal ds_read_b128
// conflicts). bo is LOCAL to a half-batch launch (b0 = batch offset).
__global__ __launch_bounds__(256) void k_score(
    const ushort_t* __restrict__ Qb, const ushort_t* __restrict__ Kb,
    const float* __restrict__ Z, const float* __restrict__ w_fuse,
    const float* __restrict__ b_fuse, ushort_t* __restrict__ S, int b0)
{
  __shared__ ushort_t Bs[64][424];
  const int tid = threadIdx.x, w = tid >> 6, lane = tid & 63;
  const int quad = lane >> 4, r = lane & 15;
  const int bo = blockIdx.z, o = bo % 6, b = b0 + bo / 6;
  const int m0 = blockIdx.y * 64 + w * 16;
  const int t0 = blockIdx.x * 64;

  // stage K rows t0..t0+63 (clamped) into LDS: 3072 chunks, 12/thread
  #pragma unroll
  for (int cc = 0; cc < 12; cc++) {
    const int idx = cc * 256 + tid;
    const int row = idx / 48, col8 = idx % 48;
    const int tr = min(t0 + row, 783);
    *(uint4*)&Bs[row][col8 * 8] =
        *(const uint4*)(Kb + ((size_t)(b * 784 + tr)) * 384 + col8 * 8);
  }

  // A: 12 frags of Q row lq, head-slice c=ks>>1 scaled by w_fuse[o,c]*scale
  const int lq = min(m0 + r, 783);
  const ushort_t* qp = Qb + ((size_t)(b * 784 + lq)) * 384 + quad * 8;
  float wfs[6];
  #pragma unroll
  for (int c = 0; c < 6; c++)
    wfs[c] = uload(w_fuse + o * 12 + c) * 0.05103103630798288f; // 384^-0.5
  bf16x8 a[12];
  #pragma unroll
  for (int ks = 0; ks < 12; ks++) {
    uint4 v = *(const uint4*)(qp + (size_t)ks * 32);
    const ushort_t* sv = (const ushort_t*)&v;
    ushort_t ov[8];
    #pragma unroll
    for (int e = 0; e < 8; e++) ov[e] = f2bf(bf2f(sv[e]) * wfs[ks >> 1]);
    a[ks] = __builtin_bit_cast(bf16x8, *(uint4*)ov);
  }
  __syncthreads();

  f32x4 acc[4] = {};
  #pragma unroll
  for (int j = 0; j < 4; j++)
    #pragma unroll
    for (int ks = 0; ks < 12; ks++)
      acc[j] = __builtin_amdgcn_mfma_f32_16x16x32_bf16(
          a[ks], *(const bf16x8*)&Bs[j * 16 + r][ks * 32 + quad * 8],
          acc[j], 0, 0, 0);

  // epilogue: + bias + bilinear res, write bf16
  const float bfu = uload(b_fuse + o);
  const float* zo = Z + ((size_t)(b * 6 + o)) * 153664;
  int p00a[4], p01a[4], p10a[4];
  float fxa[4], fya[4];
  #pragma unroll
  for (int i = 0; i < 4; i++) {
    const int l = m0 + quad * 4 + i;          // cy/cx clamps keep idx in-bounds
    const int Y = l / 28, X = l % 28;
    const float cy = fminf(fmaxf((float)Y * 0.5f - 0.25f, 0.f), 13.f);
    const float cx = fminf(fmaxf((float)X * 0.5f - 0.25f, 0.f), 13.f);
    const int y0 = (int)cy, y1 = min(y0 + 1, 13);
    const int x0 = (int)cx, x1 = min(x0 + 1, 13);
    fya[i] = cy - (float)y0;
    fxa[i] = cx - (float)x0;
    p00a[i] = (y0 * 14 + x0) * 784;
    p01a[i] = (y0 * 14 + x1) * 784;
    p10a[i] = (y1 * 14 + x0) * 784;
  }
  #pragma unroll
  for (int j = 0; j < 4; j++) {
    const int t = t0 + j * 16 + r;
    if (t < 784) {
      #pragma unroll
      for (int i = 0; i < 4; i++) {
        const int lo = m0 + quad * 4 + i;
        if (lo < 784) {
          const float z00 = zo[p00a[i] + t];
          const float z01 = zo[p01a[i] + t];
          const float z10 = zo[p10a[i] + t];
          const float z11 = zo[p10a[i] + p01a[i] - p00a[i] + t];
          const float r0 = z00 + fxa[i] * (z01 - z00);
          const float r1 = z10 + fxa[i] * (z11 - z10);
          S[((size_t)bo * 784 + lo) * 784 + t] =
              f2bf(acc[j][i] + bfu + r0 + fya[i] * (r1 - r0));
        }
      }
    }
  }
}

// ---------- Kernel 7: PV + on-the-fly softmax -------------------------------
// One wave per 16 rows x full K=784. A = exp(S_f) computed per fragment
// (no max pass: fused scores are O(1); clamp 60 guards overflow; row-sum
// accumulated in-register and divided out at the end -> P never stored).
__global__ __launch_bounds__(64) void k_pvs(
    const ushort_t* __restrict__ S, const ushort_t* __restrict__ Vt,
    ushort_t* __restrict__ O, int b0)
{
  const int lane = threadIdx.x;
  const int quad = lane >> 4, r = lane & 15;
  const int bo = blockIdx.y, o = bo % 6, b = b0 + bo / 6;
  const int m0 = blockIdx.x * 16;
  const int lq = min(m0 + r, 783);
  const ushort_t* ap = S + ((size_t)bo * 784 + lq) * 784 + quad * 8;
  const ushort_t* bp = Vt + ((size_t)(b * 384 + o * 64 + r)) * 784 + quad * 8;
  f32x4 acc[4] = {};
  float psv[8] = {};                        // 8 independent exp-sum chains
  for (int kk = 0; kk < 25; kk++) {
    const int k0 = kk * 32;
    const bool full = (kk < 24) | (quad < 2);   // tail k-width 16
    bf16x8 pa = {};
    bf16x8 bfr[4] = {};
    if (full) {
      uint4 sv4 = *(const uint4*)(ap + k0);
      const ushort_t* sv = (const ushort_t*)&sv4;
      ushort_t pv[8];
      #pragma unroll
      for (int e = 0; e < 8; e++) {
        const float p = __expf(fminf(bf2f(sv[e]), 60.f));
        psv[e] += p;
        pv[e] = f2bf(p);
      }
      pa = __builtin_bit_cast(bf16x8, *(uint4*)pv);
      #pragma unroll
      for (int nt = 0; nt < 4; nt++)
        bfr[nt] = ld_frag(bp + (size_t)nt * 16 * 784 + k0);
    }
    #pragma unroll
    for (int nt = 0; nt < 4; nt++)
      acc[nt] = __builtin_amdgcn_mfma_f32_16x16x32_bf16(pa, bfr[nt], acc[nt], 0, 0, 0);
  }
  float psum = 0.f;
  #pragma unroll
  for (int e = 0; e < 8; e++) psum += psv[e];
  psum += __shfl_xor(psum, 16);              // sum over quads -> row m0+r total
  psum += __shfl_xor(psum, 32);
  float inv[4];
  #pragma unroll
  for (int i = 0; i < 4; i++) inv[i] = 1.f / __shfl(psum, quad * 4 + i);
  #pragma unroll
  for (int nt = 0; nt < 4; nt++) {
    #pragma unroll
    for (int i = 0; i < 4; i++) {
      const int lo = m0 + quad * 4 + i;
      if (lo < 784)
        O[((size_t)(b * 784 + lo)) * 384 + o * 64 + nt * 16 + r] =
            f2bf(acc[nt][i] * inv[i]);
    }
  }
}

// ---------- host launcher ----------
extern "C" void kernel_launch(void* const* d_in, const int* in_sizes, int n_in,
                              void* d_out, int out_size, void* d_ws, size_t ws_size,
                              hipStream_t stream)
{
  const float* x        = (const float*)d_in[0];
  const float* res_attn = (const float*)d_in[1];
  const float* conv_w   = (const float*)d_in[2];
  const float* ln_g     = (const float*)d_in[3];
  const float* ln_b     = (const float*)d_in[4];
  const float* wq       = (const float*)d_in[5];
  const float* wk       = (const float*)d_in[6];
  const float* wv       = (const float*)d_in[7];
  const float* w_proj   = (const float*)d_in[8];
  const float* b_proj   = (const float*)d_in[9];
  const float* w_fuse   = (const float*)d_in[10];
  const float* b_fuse   = (const float*)d_in[11];
  float* out = (float*)d_out;

  // ws layout (bf16 units), ~80 MB total:
  // [Qb|Kb|Vt|Opre] 4xNE, weights 4xNW, Z (f32), S_f (half-batch, 29.5 MB).
  // q_ln_b/kv_b staging OVERLAID on S_f (dead before k_score runs).
  const size_t NE = (size_t)8 * 784 * 384;      // 2,408,448
  const size_t NW = 147456;
  const size_t NS = (size_t)4 * 6 * 784 * 784;  // 14,751,744 (half-batch S)
  ushort_t* Qb   = (ushort_t*)d_ws;
  ushort_t* Kb   = Qb + NE;
  ushort_t* Vt   = Kb + NE;   // (b, 384, 784)
  ushort_t* Opre = Vt + NE;
  ushort_t* wqb  = Opre + NE;
  ushort_t* wkb  = wqb + NW;
  ushort_t* wvb  = wkb + NW;
  ushort_t* wpb  = wvb + NW;
  float*    Z    = (float*)(wpb + NW);          // (b,6,196,784) f32
  ushort_t* S_f  = (ushort_t*)(Z + (size_t)8 * 6 * 153664);
  ushort_t* q_ln_b = S_f;                       // overlay
  ushort_t* kv_b   = S_f + NE;                  // overlay

  k_premix<<<dim3(1201),    dim3(256), 0, stream>>>(res_attn, w_fuse, Z);
  k_convln<<<dim3(8 * 784), dim3(384), 0, stream>>>(x, conv_w, ln_g, ln_b, q_ln_b);
  k_pool  <<<dim3(9408),    dim3(256), 0, stream>>>(x, kv_b);
  k_wcvt  <<<dim3(576),     dim3(256), 0, stream>>>(wq, wk, wv, w_proj, wqb, wkb, wvb, wpb);

  k_gemm<0><<<dim3(3, 49), dim3(256), 0, stream>>>(q_ln_b, wqb, nullptr, Qb);
  k_gemm<0><<<dim3(3, 49), dim3(256), 0, stream>>>(kv_b,   wkb, nullptr, Kb);
  k_gemm<1><<<dim3(3, 49), dim3(256), 0, stream>>>(kv_b,   wvb, nullptr, Vt);

  // two half-batch passes share one S_f buffer (stream-ordered reuse)
  for (int h = 0; h < 2; h++) {
    k_score<<<dim3(13, 13, 24), dim3(256), 0, stream>>>(
        Qb, Kb, Z, w_fuse, b_fuse, S_f, h * 4);
    k_pvs<<<dim3(49, 24), dim3(64), 0, stream>>>(S_f, Vt, Opre, h * 4);
  }

  k_gemm<2><<<dim3(3, 49), dim3(256), 0, stream>>>(Opre, wpb, b_proj, out);
}

// Round 7
// 381.991 us; speedup vs baseline: 1.3252x; 1.0410x over previous
//
#include <hip/hip_runtime.h>

typedef unsigned int uint;
typedef unsigned short ushort_t;
typedef short bf16x8 __attribute__((ext_vector_type(8)));
typedef float f32x4 __attribute__((ext_vector_type(4)));

// ---------- bf16 helpers ----------
__device__ __forceinline__ ushort_t f2bf(float f) {
  uint u = __builtin_bit_cast(uint, f);
  u += 0x7fffu + ((u >> 16) & 1u);
  return (ushort_t)(u >> 16);
}
__device__ __forceinline__ float bf2f(ushort_t s) {
  return __builtin_bit_cast(float, (uint)s << 16);
}
__device__ __forceinline__ bf16x8 ld_frag(const ushort_t* p) {
  return __builtin_bit_cast(bf16x8, *(const uint4*)p);
}
// wave-uniform load -> SGPR
__device__ __forceinline__ float uload(const float* p) {
  return __builtin_bit_cast(float,
      __builtin_amdgcn_readfirstlane(__builtin_bit_cast(int, *p)));
}

// ---------- Kernel 1: depthwise conv 3x3 s2 p1 + LayerNorm -> bf16 ----------
// 2x2 avg-pool FUSED: pool taps == conv taps (ky,kx) in {1,2}^2 (always
// in-bounds), so kv comes free with the loads already in flight.
__global__ __launch_bounds__(384) void k_convln(
    const float* __restrict__ x, const float* __restrict__ wc,
    const float* __restrict__ g, const float* __restrict__ bb,
    ushort_t* __restrict__ qout, ushort_t* __restrict__ kvout)
{
  const int b  = blockIdx.x / 784;
  const int t  = blockIdx.x % 784;
  const int oy = t / 28, ox = t % 28;
  const int c  = threadIdx.x;
  const float* xb = x + (size_t)b * 3136 * 384 + c;
  float acc = 0.f, pv = 0.f;
  #pragma unroll
  for (int ky = 0; ky < 3; ky++) {
    const int iy = 2 * oy - 1 + ky;
    const bool yok = (iy >= 0) & (iy < 56);
    #pragma unroll
    for (int kx = 0; kx < 3; kx++) {
      const int ix = 2 * ox - 1 + kx;
      if (yok & (ix >= 0) & (ix < 56)) {
        const float xv = xb[(size_t)(iy * 56 + ix) * 384];
        acc += wc[c * 9 + ky * 3 + kx] * xv;
        if ((ky >= 1) & (kx >= 1)) pv += xv;   // pool taps: iy=2oy(+1), ix=2ox(+1)
      }
    }
  }
  kvout[((size_t)b * 784 + t) * 384 + c] = f2bf(pv * 0.25f);
  float s = acc, s2 = acc * acc;
  #pragma unroll
  for (int off = 32; off >= 1; off >>= 1) {
    s  += __shfl_xor(s,  off);
    s2 += __shfl_xor(s2, off);
  }
  __shared__ float ps[6], ps2[6];
  if ((c & 63) == 0) { ps[c >> 6] = s; ps2[c >> 6] = s2; }
  __syncthreads();
  float S = 0.f, S2 = 0.f;
  #pragma unroll
  for (int i = 0; i < 6; i++) { S += ps[i]; S2 += ps2[i]; }
  const float mu  = S * (1.f / 384.f);
  const float var = S2 * (1.f / 384.f) - mu * mu;
  const float inv = rsqrtf(var + 1e-5f);
  qout[((size_t)b * 784 + t) * 384 + c] = f2bf((acc - mu) * inv * g[c] + bb[c]);
}

// ---------- Kernel 3: weights f32 -> bf16 ----------
__global__ __launch_bounds__(256) void k_wcvt(
    const float* __restrict__ a, const float* __restrict__ b,
    const float* __restrict__ c, const float* __restrict__ d,
    ushort_t* __restrict__ oa, ushort_t* __restrict__ ob,
    ushort_t* __restrict__ oc, ushort_t* __restrict__ od)
{
  const int i = blockIdx.x * 256 + threadIdx.x;
  if (i < 147456) {
    oa[i] = f2bf(a[i]); ob[i] = f2bf(b[i]);
    oc[i] = f2bf(c[i]); od[i] = f2bf(d[i]);
  }
}

// ---------- Kernel 4: dense MFMA GEMM, M=6272 N=384 K=384 ----------
template<int MODE>
__global__ __launch_bounds__(256) void k_gemm(
    const ushort_t* __restrict__ X, const ushort_t* __restrict__ W,
    const float* __restrict__ bias, void* __restrict__ Y)
{
  __shared__ ushort_t As[128][40];
  __shared__ ushort_t Bs[128][40];
  const int tid = threadIdx.x, w = tid >> 6, lane = tid & 63;
  const int quad = lane >> 4, r = lane & 15;
  const int m0 = blockIdx.y * 128, n0 = blockIdx.x * 128;
  const int wm = w >> 1, wn = w & 1;
  const int lr = tid >> 2, lc = (tid & 3) << 3;
  const ushort_t* xp = X + (size_t)(m0 + lr) * 384 + lc;
  const ushort_t* wp = W + (size_t)(n0 + lr) * 384 + lc;
  f32x4 acc[4][4] = {};
  for (int k0 = 0; k0 < 384; k0 += 32) {
    __syncthreads();
    *(uint4*)&As[lr][lc]      = *(const uint4*)(xp + k0);
    *(uint4*)&As[lr + 64][lc] = *(const uint4*)(xp + (size_t)64 * 384 + k0);
    *(uint4*)&Bs[lr][lc]      = *(const uint4*)(wp + k0);
    *(uint4*)&Bs[lr + 64][lc] = *(const uint4*)(wp + (size_t)64 * 384 + k0);
    __syncthreads();
    bf16x8 af[4], bf_[4];
    #pragma unroll
    for (int mt = 0; mt < 4; mt++) af[mt]  = *(const bf16x8*)&As[wm * 64 + mt * 16 + r][quad * 8];
    #pragma unroll
    for (int nt = 0; nt < 4; nt++) bf_[nt] = *(const bf16x8*)&Bs[wn * 64 + nt * 16 + r][quad * 8];
    #pragma unroll
    for (int mt = 0; mt < 4; mt++)
      #pragma unroll
      for (int nt = 0; nt < 4; nt++)
        acc[mt][nt] = __builtin_amdgcn_mfma_f32_16x16x32_bf16(af[mt], bf_[nt], acc[mt][nt], 0, 0, 0);
  }
  #pragma unroll
  for (int mt = 0; mt < 4; mt++) {
    #pragma unroll
    for (int nt = 0; nt < 4; nt++) {
      #pragma unroll
      for (int i = 0; i < 4; i++) {
        const int row = m0 + wm * 64 + mt * 16 + quad * 4 + i;
        const int col = n0 + wn * 64 + nt * 16 + r;
        const float v = acc[mt][nt][i];
        if constexpr (MODE == 2) {
          ((float*)Y)[(size_t)row * 384 + col] = v + bias[col];
        } else if constexpr (MODE == 0) {
          ((ushort_t*)Y)[(size_t)row * 384 + col] = f2bf(v);
        } else {
          const int bb = row / 784, tt = row % 784;
          ((ushort_t*)Y)[((size_t)bb * 384 + col) * 784 + tt] = f2bf(v);
        }
      }
    }
  }
}

// ---------- Kernel 5: premix res_attn with w_fuse[:,6:12] at source res ----
__global__ __launch_bounds__(256) void k_premix(
    const float* __restrict__ ra, const float* __restrict__ w_fuse,
    float* __restrict__ Z)
{
  const int NP = 196 * 784 / 4;
  const int idx = blockIdx.x * 256 + threadIdx.x;
  if (idx >= 8 * NP) return;
  const int b = idx / NP, st = idx % NP;
  const f32x4* rb = (const f32x4*)(ra + (size_t)b * 6 * 153664) + st;
  f32x4 v[6];
  #pragma unroll
  for (int c = 0; c < 6; c++) v[c] = rb[(size_t)c * NP];
  f32x4* zb = (f32x4*)(Z + (size_t)b * 6 * 153664) + st;
  #pragma unroll
  for (int o = 0; o < 6; o++) {
    f32x4 acc = {};
    #pragma unroll
    for (int c = 0; c < 6; c++) acc += uload(w_fuse + o * 12 + 6 + c) * v[c];
    zb[(size_t)o * NP] = acc;
  }
}

// ---------- Kernel 6: fused-score GEMM, k_gemm 128x128 skeleton -------------
// P[bo][l][t] = exp( sum_k (wf[o,c(k)]*scale*Q[b,l,k])*K[b,t,k] + b_fuse[o]
//                  + bilerp(Z[b,o],l,t) )
// Per-o head scale folded into A staging: for K-step k0, head c=k0>>6 is
// UNIFORM across the staged chunk -> one SGPR scalar, 8 muls/thread/iter.
// exp fused into epilogue (no max pass: scores O(1), clamp 60; bf16 holds
// e^60 fine and softmax normalizes relative error). 20KB LDS, 1176 blocks.
__global__ __launch_bounds__(256) void k_score(
    const ushort_t* __restrict__ Qb, const ushort_t* __restrict__ Kb,
    const float* __restrict__ Z, const float* __restrict__ w_fuse,
    const float* __restrict__ b_fuse, ushort_t* __restrict__ P, int b0)
{
  __shared__ ushort_t As[128][40];
  __shared__ ushort_t Bs[128][40];
  const int tid = threadIdx.x, w = tid >> 6, lane = tid & 63;
  const int quad = lane >> 4, r = lane & 15;
  const int bo = blockIdx.z, o = bo % 6, b = b0 + bo / 6;
  const int m0 = blockIdx.y * 128, t0 = blockIdx.x * 128;
  const int wm = w >> 1, wn = w & 1;
  const int lr = tid >> 2, lc = (tid & 3) << 3;
  const int rA0 = min(m0 + lr, 783), rA1 = min(m0 + lr + 64, 783);
  const int rB0 = min(t0 + lr, 783), rB1 = min(t0 + lr + 64, 783);
  const ushort_t* xq = Qb + (size_t)(b * 784) * 384 + lc;
  const ushort_t* xk = Kb + (size_t)(b * 784) * 384 + lc;
  float wsc[6];
  #pragma unroll
  for (int c = 0; c < 6; c++)
    wsc[c] = uload(w_fuse + o * 12 + c) * 0.05103103630798288f; // 384^-0.5

  f32x4 acc[4][4] = {};
  for (int k0 = 0; k0 < 384; k0 += 32) {
    const float ws = wsc[k0 >> 6];           // wave-uniform head scale
    __syncthreads();
    uint4 va0 = *(const uint4*)(xq + (size_t)rA0 * 384 + k0);
    uint4 va1 = *(const uint4*)(xq + (size_t)rA1 * 384 + k0);
    {
      const ushort_t* s0 = (const ushort_t*)&va0;
      const ushort_t* s1 = (const ushort_t*)&va1;
      ushort_t o0[8], o1[8];
      #pragma unroll
      for (int e = 0; e < 8; e++) {
        o0[e] = f2bf(bf2f(s0[e]) * ws);
        o1[e] = f2bf(bf2f(s1[e]) * ws);
      }
      *(uint4*)&As[lr][lc]      = *(uint4*)o0;
      *(uint4*)&As[lr + 64][lc] = *(uint4*)o1;
    }
    *(uint4*)&Bs[lr][lc]      = *(const uint4*)(xk + (size_t)rB0 * 384 + k0);
    *(uint4*)&Bs[lr + 64][lc] = *(const uint4*)(xk + (size_t)rB1 * 384 + k0);
    __syncthreads();
    bf16x8 af[4], bf_[4];
    #pragma unroll
    for (int mt = 0; mt < 4; mt++) af[mt]  = *(const bf16x8*)&As[wm * 64 + mt * 16 + r][quad * 8];
    #pragma unroll
    for (int nt = 0; nt < 4; nt++) bf_[nt] = *(const bf16x8*)&Bs[wn * 64 + nt * 16 + r][quad * 8];
    #pragma unroll
    for (int mt = 0; mt < 4; mt++)
      #pragma unroll
      for (int nt = 0; nt < 4; nt++)
        acc[mt][nt] = __builtin_amdgcn_mfma_f32_16x16x32_bf16(af[mt], bf_[nt], acc[mt][nt], 0, 0, 0);
  }

  // epilogue: + bias + bilinear res, exp, write P bf16
  const float bfu = uload(b_fuse + o);
  const float* zo = Z + ((size_t)(b * 6 + o)) * 153664;
  #pragma unroll
  for (int mt = 0; mt < 4; mt++) {
    #pragma unroll
    for (int i = 0; i < 4; i++) {
      const int lo = m0 + wm * 64 + mt * 16 + quad * 4 + i;
      if (lo < 784) {
        const int Y = lo / 28, X = lo % 28;
        const float cy = fminf(fmaxf((float)Y * 0.5f - 0.25f, 0.f), 13.f);
        const float cx = fminf(fmaxf((float)X * 0.5f - 0.25f, 0.f), 13.f);
        const int y0 = (int)cy, y1 = min(y0 + 1, 13);
        const int x0 = (int)cx, x1 = min(x0 + 1, 13);
        const float fy = cy - (float)y0, fx = cx - (float)x0;
        const int p00 = (y0 * 14 + x0) * 784, p01 = (y0 * 14 + x1) * 784;
        const int p10 = (y1 * 14 + x0) * 784, p11 = (y1 * 14 + x1) * 784;
        ushort_t* prow = P + ((size_t)bo * 784 + lo) * 784;
        #pragma unroll
        for (int nt = 0; nt < 4; nt++) {
          const int t = t0 + wn * 64 + nt * 16 + r;
          if (t < 784) {
            const float z00 = zo[p00 + t], z01 = zo[p01 + t];
            const float z10 = zo[p10 + t], z11 = zo[p11 + t];
            const float r0 = z00 + fx * (z01 - z00);
            const float r1 = z10 + fx * (z11 - z10);
            const float s = acc[mt][nt][i] + bfu + r0 + fy * (r1 - r0);
            prow[t] = f2bf(__expf(fminf(s, 60.f)));
          }
        }
      }
    }
  }
}

// ---------- Kernel 7: PV GEMM + row-sum normalize ---------------------------
// A = P (bf16, unnormalized exp) read once per row; row-sum accumulated from
// the SAME fragments (no exp here), divided out at the end.
__global__ __launch_bounds__(256) void k_pvs(
    const ushort_t* __restrict__ P, const ushort_t* __restrict__ Vt,
    ushort_t* __restrict__ O, int b0)
{
  const int tid = threadIdx.x, w = tid >> 6, lane = tid & 63;
  const int quad = lane >> 4, r = lane & 15;
  const int bo = blockIdx.y, o = bo % 6, b = b0 + bo / 6;
  const int m0 = blockIdx.x * 64 + w * 16;
  const int lq = min(m0 + r, 783);
  const ushort_t* ap = P + ((size_t)bo * 784 + lq) * 784 + quad * 8;
  const ushort_t* bp = Vt + ((size_t)(b * 384 + o * 64 + r)) * 784 + quad * 8;
  f32x4 acc[4] = {};
  float ps = 0.f;
  for (int kk = 0; kk < 25; kk++) {
    const int k0 = kk * 32;
    const bool full = (kk < 24) | (quad < 2);  // tail k-width 16
    bf16x8 af = {}, bfr[4] = {};
    if (full) {
      af = ld_frag(ap + k0);
      const ushort_t* sv = (const ushort_t*)&af;
      #pragma unroll
      for (int e = 0; e < 8; e++) ps += bf2f(sv[e]);
      #pragma unroll
      for (int nt = 0; nt < 4; nt++) bfr[nt] = ld_frag(bp + (size_t)nt * 16 * 784 + k0);
    }
    #pragma unroll
    for (int nt = 0; nt < 4; nt++)
      acc[nt] = __builtin_amdgcn_mfma_f32_16x16x32_bf16(af, bfr[nt], acc[nt], 0, 0, 0);
  }
  ps += __shfl_xor(ps, 16);                  // sum over quads -> row m0+r total
  ps += __shfl_xor(ps, 32);
  float inv[4];
  #pragma unroll
  for (int i = 0; i < 4; i++) inv[i] = 1.f / __shfl(ps, quad * 4 + i);
  #pragma unroll
  for (int nt = 0; nt < 4; nt++) {
    #pragma unroll
    for (int i = 0; i < 4; i++) {
      const int lo = m0 + quad * 4 + i;
      if (lo < 784)
        O[((size_t)(b * 784 + lo)) * 384 + o * 64 + nt * 16 + r] =
            f2bf(acc[nt][i] * inv[i]);
    }
  }
}

// ---------- host launcher ----------
extern "C" void kernel_launch(void* const* d_in, const int* in_sizes, int n_in,
                              void* d_out, int out_size, void* d_ws, size_t ws_size,
                              hipStream_t stream)
{
  const float* x        = (const float*)d_in[0];
  const float* res_attn = (const float*)d_in[1];
  const float* conv_w   = (const float*)d_in[2];
  const float* ln_g     = (const float*)d_in[3];
  const float* ln_b     = (const float*)d_in[4];
  const float* wq       = (const float*)d_in[5];
  const float* wk       = (const float*)d_in[6];
  const float* wv       = (const float*)d_in[7];
  const float* w_proj   = (const float*)d_in[8];
  const float* b_proj   = (const float*)d_in[9];
  const float* w_fuse   = (const float*)d_in[10];
  const float* b_fuse   = (const float*)d_in[11];
  float* out = (float*)d_out;

  // ws layout (bf16 units), ~80 MB: [Qb|Kb|Vt|Opre] + weights + Z(f32) +
  // P (half-batch, 29.5 MB). conv/pool staging OVERLAID on P (dead by then).
  const size_t NE = (size_t)8 * 784 * 384;      // 2,408,448
  const size_t NW = 147456;
  ushort_t* Qb   = (ushort_t*)d_ws;
  ushort_t* Kb   = Qb + NE;
  ushort_t* Vt   = Kb + NE;   // (b, 384, 784)
  ushort_t* Opre = Vt + NE;
  ushort_t* wqb  = Opre + NE;
  ushort_t* wkb  = wqb + NW;
  ushort_t* wvb  = wkb + NW;
  ushort_t* wpb  = wvb + NW;
  float*    Z    = (float*)(wpb + NW);          // (b,6,196,784) f32
  ushort_t* P_f  = (ushort_t*)(Z + (size_t)8 * 6 * 153664);
  ushort_t* q_ln_b = P_f;                       // overlay
  ushort_t* kv_b   = P_f + NE;                  // overlay

  k_premix<<<dim3(1201),    dim3(256), 0, stream>>>(res_attn, w_fuse, Z);
  k_convln<<<dim3(8 * 784), dim3(384), 0, stream>>>(x, conv_w, ln_g, ln_b, q_ln_b, kv_b);
  k_wcvt  <<<dim3(576),     dim3(256), 0, stream>>>(wq, wk, wv, w_proj, wqb, wkb, wvb, wpb);

  k_gemm<0><<<dim3(3, 49), dim3(256), 0, stream>>>(q_ln_b, wqb, nullptr, Qb);
  k_gemm<0><<<dim3(3, 49), dim3(256), 0, stream>>>(kv_b,   wkb, nullptr, Kb);
  k_gemm<1><<<dim3(3, 49), dim3(256), 0, stream>>>(kv_b,   wvb, nullptr, Vt);

  // two half-batch passes share one P buffer (stream-ordered reuse)
  for (int h = 0; h < 2; h++) {
    k_score<<<dim3(7, 7, 24), dim3(256), 0, stream>>>(
        Qb, Kb, Z, w_fuse, b_fuse, P_f, h * 4);
    k_pvs<<<dim3(13, 24), dim3(256), 0, stream>>>(P_f, Vt, Opre, h * 4);
  }

  k_gemm<2><<<dim3(3, 49), dim3(256), 0, stream>>>(Opre, wpb, b_proj, out);
}

// Round 8
// 319.634 us; speedup vs baseline: 1.5837x; 1.1951x over previous
//
#include <hip/hip_runtime.h>

typedef unsigned int uint;
typedef unsigned short ushort_t;
typedef short bf16x8 __attribute__((ext_vector_type(8)));
typedef float f32x4 __attribute__((ext_vector_type(4)));

// ---------- bf16 helpers ----------
__device__ __forceinline__ ushort_t f2bf(float f) {
  uint u = __builtin_bit_cast(uint, f);
  u += 0x7fffu + ((u >> 16) & 1u);
  return (ushort_t)(u >> 16);
}
__device__ __forceinline__ float bf2f(ushort_t s) {
  return __builtin_bit_cast(float, (uint)s << 16);
}
__device__ __forceinline__ bf16x8 ld_frag(const ushort_t* p) {
  return __builtin_bit_cast(bf16x8, *(const uint4*)p);
}

// ---------- Kernel 1: depthwise conv 3x3 s2 p1 + LayerNorm -> bf16 ----------
// 2x2 avg-pool FUSED (validated round 7): pool taps == conv taps
// (ky,kx) in {1,2}^2, always in-bounds -> kv comes free with loads in flight.
__global__ __launch_bounds__(384) void k_convln(
    const float* __restrict__ x, const float* __restrict__ wc,
    const float* __restrict__ g, const float* __restrict__ bb,
    ushort_t* __restrict__ qout, ushort_t* __restrict__ kvout)
{
  const int b  = blockIdx.x / 784;
  const int t  = blockIdx.x % 784;
  const int oy = t / 28, ox = t % 28;
  const int c  = threadIdx.x;
  const float* xb = x + (size_t)b * 3136 * 384 + c;
  float acc = 0.f, pv = 0.f;
  #pragma unroll
  for (int ky = 0; ky < 3; ky++) {
    const int iy = 2 * oy - 1 + ky;
    const bool yok = (iy >= 0) & (iy < 56);
    #pragma unroll
    for (int kx = 0; kx < 3; kx++) {
      const int ix = 2 * ox - 1 + kx;
      if (yok & (ix >= 0) & (ix < 56)) {
        const float xv = xb[(size_t)(iy * 56 + ix) * 384];
        acc += wc[c * 9 + ky * 3 + kx] * xv;
        if ((ky >= 1) & (kx >= 1)) pv += xv;   // pool taps
      }
    }
  }
  kvout[((size_t)b * 784 + t) * 384 + c] = f2bf(pv * 0.25f);
  float s = acc, s2 = acc * acc;
  #pragma unroll
  for (int off = 32; off >= 1; off >>= 1) {
    s  += __shfl_xor(s,  off);
    s2 += __shfl_xor(s2, off);
  }
  __shared__ float ps[6], ps2[6];
  if ((c & 63) == 0) { ps[c >> 6] = s; ps2[c >> 6] = s2; }
  __syncthreads();
  float S = 0.f, S2 = 0.f;
  #pragma unroll
  for (int i = 0; i < 6; i++) { S += ps[i]; S2 += ps2[i]; }
  const float mu  = S * (1.f / 384.f);
  const float var = S2 * (1.f / 384.f) - mu * mu;
  const float inv = rsqrtf(var + 1e-5f);
  qout[((size_t)b * 784 + t) * 384 + c] = f2bf((acc - mu) * inv * g[c] + bb[c]);
}

// ---------- Kernel 2: weights f32 -> bf16 ----------
__global__ __launch_bounds__(256) void k_wcvt(
    const float* __restrict__ a, const float* __restrict__ b,
    const float* __restrict__ c, const float* __restrict__ d,
    ushort_t* __restrict__ oa, ushort_t* __restrict__ ob,
    ushort_t* __restrict__ oc, ushort_t* __restrict__ od)
{
  const int i = blockIdx.x * 256 + threadIdx.x;
  if (i < 147456) {
    oa[i] = f2bf(a[i]); ob[i] = f2bf(b[i]);
    oc[i] = f2bf(c[i]); od[i] = f2bf(d[i]);
  }
}

// ---------- Kernel 3: dense MFMA GEMM, M=6272 N=384 K=384 ----------
// MODE 0: bf16 row-major out; MODE 1: bf16 transposed (b,384,784) out (V);
// MODE 2: f32 +bias out.
template<int MODE>
__global__ __launch_bounds__(256) void k_gemm(
    const ushort_t* __restrict__ X, const ushort_t* __restrict__ W,
    const float* __restrict__ bias, void* __restrict__ Y)
{
  __shared__ ushort_t As[128][40];  // pad: row stride 20 dw (2-way, free)
  __shared__ ushort_t Bs[128][40];
  const int tid = threadIdx.x, w = tid >> 6, lane = tid & 63;
  const int quad = lane >> 4, r = lane & 15;
  const int m0 = blockIdx.y * 128, n0 = blockIdx.x * 128;
  const int wm = w >> 1, wn = w & 1;
  const int lr = tid >> 2, lc = (tid & 3) << 3;
  const ushort_t* xp = X + (size_t)(m0 + lr) * 384 + lc;
  const ushort_t* wp = W + (size_t)(n0 + lr) * 384 + lc;
  f32x4 acc[4][4] = {};
  for (int k0 = 0; k0 < 384; k0 += 32) {
    __syncthreads();
    *(uint4*)&As[lr][lc]      = *(const uint4*)(xp + k0);
    *(uint4*)&As[lr + 64][lc] = *(const uint4*)(xp + (size_t)64 * 384 + k0);
    *(uint4*)&Bs[lr][lc]      = *(const uint4*)(wp + k0);
    *(uint4*)&Bs[lr + 64][lc] = *(const uint4*)(wp + (size_t)64 * 384 + k0);
    __syncthreads();
    bf16x8 af[4], bf_[4];
    #pragma unroll
    for (int mt = 0; mt < 4; mt++) af[mt]  = *(const bf16x8*)&As[wm * 64 + mt * 16 + r][quad * 8];
    #pragma unroll
    for (int nt = 0; nt < 4; nt++) bf_[nt] = *(const bf16x8*)&Bs[wn * 64 + nt * 16 + r][quad * 8];
    #pragma unroll
    for (int mt = 0; mt < 4; mt++)
      #pragma unroll
      for (int nt = 0; nt < 4; nt++)
        acc[mt][nt] = __builtin_amdgcn_mfma_f32_16x16x32_bf16(af[mt], bf_[nt], acc[mt][nt], 0, 0, 0);
  }
  #pragma unroll
  for (int mt = 0; mt < 4; mt++) {
    #pragma unroll
    for (int nt = 0; nt < 4; nt++) {
      #pragma unroll
      for (int i = 0; i < 4; i++) {
        const int row = m0 + wm * 64 + mt * 16 + quad * 4 + i;
        const int col = n0 + wn * 64 + nt * 16 + r;
        const float v = acc[mt][nt][i];
        if constexpr (MODE == 2) {
          ((float*)Y)[(size_t)row * 384 + col] = v + bias[col];
        } else if constexpr (MODE == 0) {
          ((ushort_t*)Y)[(size_t)row * 384 + col] = f2bf(v);
        } else {
          const int bb = row / 784, tt = row % 784;
          ((ushort_t*)Y)[((size_t)bb * 384 + col) * 784 + tt] = f2bf(v);
        }
      }
    }
  }
}

// ---------- Kernel 4: QK^T batched MFMA (48 batches, M=N=784, K=64) ----------
// Round-0 verified. No LDS: K=64 -> 2 k-steps, frags direct from L2-hot global.
// S layout: (b, l, c, t) bf16, scaled.
__global__ __launch_bounds__(256) void k_qk(
    const ushort_t* __restrict__ Qb, const ushort_t* __restrict__ Kb,
    ushort_t* __restrict__ S)
{
  const int tid = threadIdx.x, w = tid >> 6, lane = tid & 63;
  const int quad = lane >> 4, r = lane & 15;
  const int bh = blockIdx.z, b = bh / 6, h = bh % 6;
  const int m0 = blockIdx.y * 64 + w * 16;
  const int t0 = blockIdx.x * 112;
  const int lq = min(m0 + r, 783);
  const ushort_t* qp = Qb + (size_t)(b * 784 + lq) * 384 + h * 64 + quad * 8;
  const bf16x8 a0 = ld_frag(qp), a1 = ld_frag(qp + 32);
  f32x4 acc[7] = {};
  #pragma unroll
  for (int j = 0; j < 7; j++) {
    const int t = t0 + j * 16 + r;
    const ushort_t* kp = Kb + (size_t)(b * 784 + t) * 384 + h * 64 + quad * 8;
    acc[j] = __builtin_amdgcn_mfma_f32_16x16x32_bf16(a0, ld_frag(kp),      acc[j], 0, 0, 0);
    acc[j] = __builtin_amdgcn_mfma_f32_16x16x32_bf16(a1, ld_frag(kp + 32), acc[j], 0, 0, 0);
  }
  const float scale = 0.05103103630798288f; // 384^-0.5
  #pragma unroll
  for (int j = 0; j < 7; j++) {
    #pragma unroll
    for (int i = 0; i < 4; i++) {
      const int lo = m0 + quad * 4 + i;
      if (lo < 784)
        S[((size_t)(b * 784 + lo) * 6 + h) * 784 + t0 + j * 16 + r] = f2bf(acc[j][i] * scale);
    }
  }
}

// ---------- Kernel 5: fuse heads + bilinear res_attn + softmax (in place) ----
// Round-0 verified 74us kernel MINUS the max pass: scores are O(1) (clamp 60
// guards exp; validated rounds 5/7), so exp directly + f32 row-sum + divide.
// One block per (b,l); each thread owns its own t columns -> race-free.
__global__ __launch_bounds__(256) void k_fuse(
    ushort_t* __restrict__ S, const float* __restrict__ ra,
    const float* __restrict__ w_fuse, const float* __restrict__ b_fuse)
{
  const int tid = threadIdx.x;
  const int bl = blockIdx.x, b = bl / 784, l = bl % 784;
  __shared__ float wf[72], bfu[6];
  __shared__ float reds[4][6];
  if (tid < 72) wf[tid] = w_fuse[tid];
  if (tid < 6)  bfu[tid] = b_fuse[tid];
  __syncthreads();

  const int Y = l / 28, X = l % 28;
  const float cy = fminf(fmaxf((float)Y * 0.5f - 0.25f, 0.f), 13.f);
  const float cx = fminf(fmaxf((float)X * 0.5f - 0.25f, 0.f), 13.f);
  const int y0 = (int)cy, y1 = min(y0 + 1, 13);
  const int x0 = (int)cx, x1 = min(x0 + 1, 13);
  const float fy = cy - (float)y0, fx = cx - (float)x0;
  const float w00 = (1.f - fy) * (1.f - fx), w01 = (1.f - fy) * fx;
  const float w10 = fy * (1.f - fx),         w11 = fy * fx;
  const int p00 = (y0 * 14 + x0) * 784, p01 = (y0 * 14 + x1) * 784;
  const int p10 = (y1 * 14 + x0) * 784, p11 = (y1 * 14 + x1) * 784;

  ushort_t* Srow = S + (size_t)bl * 6 * 784;
  const float* rab = ra + (size_t)b * 6 * 196 * 784;

  float F[4][6];
  float sm[6] = {};
  #pragma unroll
  for (int j = 0; j < 4; j++) {
    const int t = tid + j * 256;
    if (t < 784) {
      float a[6];
      #pragma unroll
      for (int o = 0; o < 6; o++) a[o] = bfu[o];
      #pragma unroll
      for (int c = 0; c < 6; c++) {
        const float* rc = rab + (size_t)c * (196 * 784);
        const float rx = w00 * rc[p00 + t] + w01 * rc[p01 + t]
                       + w10 * rc[p10 + t] + w11 * rc[p11 + t];
        const float sv = bf2f(Srow[c * 784 + t]);
        #pragma unroll
        for (int o = 0; o < 6; o++) a[o] += wf[o * 12 + c] * sv + wf[o * 12 + 6 + c] * rx;
      }
      #pragma unroll
      for (int o = 0; o < 6; o++) {
        const float p = __expf(fminf(a[o], 60.f));   // no max pass: scores O(1)
        F[j][o] = p; sm[o] += p;
      }
    } else {
      #pragma unroll
      for (int o = 0; o < 6; o++) F[j][o] = 0.f;
    }
  }
  // block sum per o
  #pragma unroll
  for (int o = 0; o < 6; o++) {
    #pragma unroll
    for (int off = 32; off >= 1; off >>= 1) sm[o] += __shfl_xor(sm[o], off);
  }
  if ((tid & 63) == 0) {
    #pragma unroll
    for (int o = 0; o < 6; o++) reds[tid >> 6][o] = sm[o];
  }
  __syncthreads();
  float inv[6];
  #pragma unroll
  for (int o = 0; o < 6; o++)
    inv[o] = 1.f / (reds[0][o] + reds[1][o] + reds[2][o] + reds[3][o]);
  #pragma unroll
  for (int j = 0; j < 4; j++) {
    const int t = tid + j * 256;
    if (t < 784) {
      #pragma unroll
      for (int o = 0; o < 6; o++) Srow[o * 784 + t] = f2bf(F[j][o] * inv[o]);
    }
  }
}

// ---------- Kernel 6: PV batched MFMA (48 batches, M=784 N=64 K=784) --------
// Round-0 verified. P layout (b,l,o,t); Vt layout (b,384,784). Out bf16.
__global__ __launch_bounds__(256) void k_pv(
    const ushort_t* __restrict__ P, const ushort_t* __restrict__ Vt,
    ushort_t* __restrict__ O)
{
  const int tid = threadIdx.x, w = tid >> 6, lane = tid & 63;
  const int quad = lane >> 4, r = lane & 15;
  const int bo = blockIdx.y, b = bo / 6, o = bo % 6;
  const int m0 = blockIdx.x * 64 + w * 16;
  const int lq = min(m0 + r, 783);
  const ushort_t* ap = P + ((size_t)(b * 784 + lq) * 6 + o) * 784 + quad * 8;
  const ushort_t* bp = Vt + ((size_t)b * 384 + o * 64 + r) * 784 + quad * 8;
  f32x4 acc[4] = {};
  for (int kk = 0; kk < 25; kk++) {
    const int k0 = kk * 32;
    const bool full = (kk < 24) | (quad < 2);  // tail: K rem 16, quads 2,3 -> 0
    bf16x8 af = {}, bf_[4] = {};
    if (full) {
      af = ld_frag(ap + k0);
      #pragma unroll
      for (int nt = 0; nt < 4; nt++) bf_[nt] = ld_frag(bp + (size_t)nt * 16 * 784 + k0);
    }
    #pragma unroll
    for (int nt = 0; nt < 4; nt++)
      acc[nt] = __builtin_amdgcn_mfma_f32_16x16x32_bf16(af, bf_[nt], acc[nt], 0, 0, 0);
  }
  #pragma unroll
  for (int nt = 0; nt < 4; nt++) {
    #pragma unroll
    for (int i = 0; i < 4; i++) {
      const int lo = m0 + quad * 4 + i;
      if (lo < 784)
        O[(size_t)(b * 784 + lo) * 384 + o * 64 + nt * 16 + r] = f2bf(acc[nt][i]);
    }
  }
}

// ---------- host launcher ----------
extern "C" void kernel_launch(void* const* d_in, const int* in_sizes, int n_in,
                              void* d_out, int out_size, void* d_ws, size_t ws_size,
                              hipStream_t stream)
{
  const float* x        = (const float*)d_in[0];
  const float* res_attn = (const float*)d_in[1];
  const float* conv_w   = (const float*)d_in[2];
  const float* ln_g     = (const float*)d_in[3];
  const float* ln_b     = (const float*)d_in[4];
  const float* wq       = (const float*)d_in[5];
  const float* wk       = (const float*)d_in[6];
  const float* wv       = (const float*)d_in[7];
  const float* w_proj   = (const float*)d_in[8];
  const float* b_proj   = (const float*)d_in[9];
  const float* w_fuse   = (const float*)d_in[10];
  const float* b_fuse   = (const float*)d_in[11];
  float* out = (float*)d_out;

  // ws layout (bf16 elements), ~89 MB — round-0 proven layout
  const size_t NE = (size_t)8 * 784 * 384;      // 2,408,448
  const size_t NW = 147456;
  ushort_t* q_ln_b = (ushort_t*)d_ws;
  ushort_t* kv_b   = q_ln_b + NE;
  ushort_t* Qb     = kv_b + NE;
  ushort_t* Kb     = Qb + NE;
  ushort_t* Vt     = Kb + NE;   // (b, 384, 784)
  ushort_t* Opre   = Vt + NE;
  ushort_t* wqb    = Opre + NE;
  ushort_t* wkb    = wqb + NW;
  ushort_t* wvb    = wkb + NW;
  ushort_t* wpb    = wvb + NW;
  ushort_t* S      = wpb + NW;  // (b, 784, 6, 784) -> becomes P in place

  k_convln<<<dim3(8 * 784), dim3(384), 0, stream>>>(x, conv_w, ln_g, ln_b, q_ln_b, kv_b);
  k_wcvt  <<<dim3(576),     dim3(256), 0, stream>>>(wq, wk, wv, w_proj, wqb, wkb, wvb, wpb);

  k_gemm<0><<<dim3(3, 49), dim3(256), 0, stream>>>(q_ln_b, wqb, nullptr, Qb);
  k_gemm<0><<<dim3(3, 49), dim3(256), 0, stream>>>(kv_b,   wkb, nullptr, Kb);
  k_gemm<1><<<dim3(3, 49), dim3(256), 0, stream>>>(kv_b,   wvb, nullptr, Vt);

  k_qk  <<<dim3(7, 13, 48), dim3(256), 0, stream>>>(Qb, Kb, S);
  k_fuse<<<dim3(8 * 784),   dim3(256), 0, stream>>>(S, res_attn, w_fuse, b_fuse);
  k_pv  <<<dim3(13, 48),    dim3(256), 0, stream>>>(S, Vt, Opre);

  k_gemm<2><<<dim3(3, 49), dim3(256), 0, stream>>>(Opre, wpb, b_proj, out);
}